// Round 2
// baseline (924.611 us; speedup 1.0000x reference)
//
#include <hip/hip_runtime.h>
#include <math.h>

#define N_NODES 50000
#define N_EDGES 800000
#define NCLASS 40

// ---------------- edge dtype normalize ----------------
// If edges arrive as int64, odd int32 words (high words) are all 0.
// If int32, odd words are random src values in [0,50000) -> ballot != 0.
__global__ void detect_i64(const int* __restrict__ raw, int* __restrict__ flag) {
  int t = threadIdx.x;
  int v = raw[2 * t + 1];
  unsigned long long any = __ballot(v != 0);
  if (t == 0) flag[0] = (any == 0ULL) ? 1 : 0;
}

__global__ void norm_edges(const int* __restrict__ raw, const int* __restrict__ flag,
                           int* __restrict__ s32, int* __restrict__ d32) {
  int e = blockIdx.x * blockDim.x + threadIdx.x;
  if (e >= N_EDGES) return;
  if (flag[0]) {  // int64 layout: src[e]=word[2e], dst[e]=word[2E+2e]
    s32[e] = raw[2 * e];
    d32[e] = raw[2 * N_EDGES + 2 * e];
  } else {        // int32 layout
    s32[e] = raw[e];
    d32[e] = raw[N_EDGES + e];
  }
}

// ---------------- CSR build (group edges by dst) ----------------
__global__ void count_deg(const int* __restrict__ d32, int* __restrict__ deg) {
  int e = blockIdx.x * blockDim.x + threadIdx.x;
  if (e < N_EDGES) atomicAdd(&deg[d32[e]], 1);
}

__global__ void scan_bsum(const int* __restrict__ deg, int* __restrict__ bsums) {
  __shared__ int sm[256];
  int t = threadIdx.x;
  int i = blockIdx.x * 256 + t;
  sm[t] = (i < N_NODES) ? deg[i] : 0;
  __syncthreads();
  for (int off = 128; off > 0; off >>= 1) {
    if (t < off) sm[t] += sm[t + off];
    __syncthreads();
  }
  if (t == 0) bsums[blockIdx.x] = sm[0];
}

__global__ void scan_offsets(int* __restrict__ bsums, int* __restrict__ rowp, int nb) {
  __shared__ int sm[256];
  int t = threadIdx.x;
  int v = (t < nb) ? bsums[t] : 0;
  sm[t] = v;
  __syncthreads();
  for (int off = 1; off < 256; off <<= 1) {
    int add = (t >= off) ? sm[t - off] : 0;
    __syncthreads();
    sm[t] += add;
    __syncthreads();
  }
  if (t < nb) bsums[t] = sm[t] - v;  // exclusive block offsets
  if (t == 0) rowp[N_NODES] = N_EDGES;
}

__global__ void scan_final(const int* __restrict__ deg, const int* __restrict__ bsums,
                           int* __restrict__ rowp, int* __restrict__ cursor) {
  __shared__ int sm[256];
  int t = threadIdx.x;
  int i = blockIdx.x * 256 + t;
  int v = (i < N_NODES) ? deg[i] : 0;
  sm[t] = v;
  __syncthreads();
  for (int off = 1; off < 256; off <<= 1) {
    int add = (t >= off) ? sm[t - off] : 0;
    __syncthreads();
    sm[t] += add;
    __syncthreads();
  }
  int excl = sm[t] - v + bsums[blockIdx.x];
  if (i < N_NODES) { rowp[i] = excl; cursor[i] = excl; }
}

__global__ void scatter_edges(const int* __restrict__ s32, const int* __restrict__ d32,
                              int* __restrict__ cursor, int* __restrict__ srcs) {
  int e = blockIdx.x * blockDim.x + threadIdx.x;
  if (e >= N_EDGES) return;
  int d = d32[e];
  int pos = atomicAdd(&cursor[d], 1);
  srcs[pos] = s32[e];
}

// ---------------- fp32 tiled GEMM: C[N,Mout] = A[N,256] @ W[256,Mout] ----------------
__global__ __launch_bounds__(256) void gemm_k256(const float* __restrict__ A,
                                                 const float* __restrict__ W,
                                                 float* __restrict__ C, int Mout) {
  __shared__ float As[16][68];  // As[k][row]
  __shared__ float Bs[16][68];  // Bs[k][col]
  int t = threadIdx.x;
  int tx = t & 15, ty = t >> 4;
  int row0 = blockIdx.x * 64, col0 = blockIdx.y * 64;
  int a_r = t >> 2, a_k = (t & 3) << 2;
  int b_k = t >> 4, b_n = (t & 15) << 2;
  float acc[4][4] = {};
  for (int k0 = 0; k0 < 256; k0 += 16) {
    float4 av = make_float4(0.f, 0.f, 0.f, 0.f);
    int grow = row0 + a_r;
    if (grow < N_NODES)
      av = *reinterpret_cast<const float4*>(A + (size_t)grow * 256 + k0 + a_k);
    As[a_k + 0][a_r] = av.x;
    As[a_k + 1][a_r] = av.y;
    As[a_k + 2][a_r] = av.z;
    As[a_k + 3][a_r] = av.w;
    float4 bv = make_float4(0.f, 0.f, 0.f, 0.f);
    int gcol = col0 + b_n;
    if (gcol < Mout)  // Mout % 4 == 0, so full float4 is in-bounds
      bv = *reinterpret_cast<const float4*>(W + (size_t)(k0 + b_k) * Mout + gcol);
    *reinterpret_cast<float4*>(&Bs[b_k][b_n]) = bv;
    __syncthreads();
#pragma unroll
    for (int k = 0; k < 16; ++k) {
      float4 a = *reinterpret_cast<const float4*>(&As[k][ty * 4]);
      float4 b = *reinterpret_cast<const float4*>(&Bs[k][tx * 4]);
      acc[0][0] += a.x * b.x; acc[0][1] += a.x * b.y; acc[0][2] += a.x * b.z; acc[0][3] += a.x * b.w;
      acc[1][0] += a.y * b.x; acc[1][1] += a.y * b.y; acc[1][2] += a.y * b.z; acc[1][3] += a.y * b.w;
      acc[2][0] += a.z * b.x; acc[2][1] += a.z * b.y; acc[2][2] += a.z * b.z; acc[2][3] += a.z * b.w;
      acc[3][0] += a.w * b.x; acc[3][1] += a.w * b.y; acc[3][2] += a.w * b.z; acc[3][3] += a.w * b.w;
    }
    __syncthreads();
  }
  int c = col0 + tx * 4;
  if (c + 3 < Mout) {
#pragma unroll
    for (int i = 0; i < 4; ++i) {
      int r = row0 + ty * 4 + i;
      if (r < N_NODES) {
        float4 v = make_float4(acc[i][0], acc[i][1], acc[i][2], acc[i][3]);
        *reinterpret_cast<float4*>(C + (size_t)r * Mout + c) = v;
      }
    }
  }
}

// ---------------- el/er = per-(node,head) dots with al/ar ----------------
__global__ __launch_bounds__(256) void elr_heads(const float* __restrict__ h,
                                                 const float* __restrict__ al,
                                                 const float* __restrict__ ar,
                                                 float* __restrict__ el, float* __restrict__ er) {
  int n = blockIdx.x, t = threadIdx.x;  // t = head*64 + d
  float hv = h[(size_t)n * 256 + t];
  float pl = hv * al[t];
  float pr = hv * ar[t];
  for (int off = 32; off > 0; off >>= 1) {
    pl += __shfl_down(pl, off);
    pr += __shfl_down(pr, off);
  }
  if ((t & 63) == 0) {
    el[n * 4 + (t >> 6)] = pl;
    er[n * 4 + (t >> 6)] = pr;
  }
}

__global__ __launch_bounds__(64) void elr_cls(const float* __restrict__ h3,
                                              const float* __restrict__ al,
                                              const float* __restrict__ ar,
                                              float* __restrict__ el, float* __restrict__ er) {
  int n = blockIdx.x, t = threadIdx.x;
  bool act = t < NCLASS;
  float hv = act ? h3[(size_t)n * NCLASS + t] : 0.f;
  float pl = act ? hv * al[t] : 0.f;
  float pr = act ? hv * ar[t] : 0.f;
  for (int off = 32; off > 0; off >>= 1) {
    pl += __shfl_down(pl, off);
    pr += __shfl_down(pr, off);
  }
  if (t == 0) { el[n] = pl; er[n] = pr; }
}

// ---------------- per-dst online-softmax aggregation (+bias+ELU) ----------------
__global__ __launch_bounds__(256) void agg_heads(const float* __restrict__ h,
                                                 const float* __restrict__ el,
                                                 const float* __restrict__ er,
                                                 const float* __restrict__ bias,
                                                 const int* __restrict__ rowp,
                                                 const int* __restrict__ srcs,
                                                 float* __restrict__ o) {
  int n = blockIdx.x, t = threadIdx.x;  // t = head*64 + d
  int head = t >> 6;
  int i0 = rowp[n], i1 = rowp[n + 1];
  float ern = er[n * 4 + head];
  float m = -INFINITY, l = 0.f, acc = 0.f;
  for (int i = i0; i < i1; ++i) {
    int s = srcs[i];
    float e = el[s * 4 + head] + ern;
    e = (e >= 0.f) ? e : 0.2f * e;  // leaky_relu 0.2
    float hv = h[(size_t)s * 256 + t];
    float nm = fmaxf(m, e);
    float sc = __expf(m - nm);
    float w = __expf(e - nm);
    acc = acc * sc + w * hv;
    l = l * sc + w;
    m = nm;
  }
  float v = (l > 0.f) ? (acc / l) : 0.f;
  v += bias[t];
  v = (v > 0.f) ? v : (__expf(v) - 1.f);  // ELU
  o[(size_t)n * 256 + t] = v;
}

// layer 3: aggregate (1 head, 40 dims) + bias, then fused log_softmax
__global__ __launch_bounds__(64) void agg_cls(const float* __restrict__ h3,
                                              const float* __restrict__ el,
                                              const float* __restrict__ er,
                                              const float* __restrict__ bias,
                                              const int* __restrict__ rowp,
                                              const int* __restrict__ srcs,
                                              float* __restrict__ out) {
  int n = blockIdx.x, t = threadIdx.x;
  bool act = t < NCLASS;
  int i0 = rowp[n], i1 = rowp[n + 1];
  float ern = er[n];
  float m = -INFINITY, l = 0.f, acc = 0.f;
  for (int i = i0; i < i1; ++i) {
    int s = srcs[i];
    float e = el[s] + ern;
    e = (e >= 0.f) ? e : 0.2f * e;
    float hv = act ? h3[(size_t)s * NCLASS + t] : 0.f;
    float nm = fmaxf(m, e);
    float sc = __expf(m - nm);
    float w = __expf(e - nm);
    acc = acc * sc + w * hv;
    l = l * sc + w;
    m = nm;
  }
  float z = ((l > 0.f) ? (acc / l) : 0.f) + (act ? bias[t] : 0.f);
  float zz = act ? z : -INFINITY;
  float mx = zz;
  for (int off = 32; off > 0; off >>= 1) mx = fmaxf(mx, __shfl_xor(mx, off));
  float ex = act ? __expf(z - mx) : 0.f;
  float sum = ex;
  for (int off = 32; off > 0; off >>= 1) sum += __shfl_xor(sum, off);
  if (act) out[(size_t)n * NCLASS + t] = z - mx - __logf(sum);
}

extern "C" void kernel_launch(void* const* d_in, const int* in_sizes, int n_in,
                              void* d_out, int out_size, void* d_ws, size_t ws_size,
                              hipStream_t stream) {
  const float* x   = (const float*)d_in[0];
  const int* edges = (const int*)d_in[1];
  const float* W1  = (const float*)d_in[2];
  const float* al1 = (const float*)d_in[3];
  const float* ar1 = (const float*)d_in[4];
  const float* b1  = (const float*)d_in[5];
  const float* W2  = (const float*)d_in[6];
  const float* al2 = (const float*)d_in[7];
  const float* ar2 = (const float*)d_in[8];
  const float* b2  = (const float*)d_in[9];
  const float* W3  = (const float*)d_in[10];
  const float* al3 = (const float*)d_in[11];
  const float* ar3 = (const float*)d_in[12];
  const float* b3  = (const float*)d_in[13];
  float* out = (float*)d_out;

  const size_t N = N_NODES, E = N_EDGES;
  float* h  = (float*)d_ws;           // [N,256]
  float* o  = h + N * 256;            // [N,256]
  float* h3 = o + N * 256;            // [N,40]
  float* el = h3 + N * 40;            // [N,4] (layer3 uses [N,1])
  float* er = el + N * 4;             // [N,4]
  int* rowp   = (int*)(er + N * 4);   // [N+1]
  int* cursor = rowp + (N + 1);       // [N]
  int* srcs   = cursor + N;           // [E]
  int* deg    = srcs + E;             // [N]
  int* bsums  = deg + N;              // [256]
  int* s32    = bsums + 256;          // [E]
  int* d32    = s32 + E;              // [E]
  int* flag   = d32 + E;              // [1]

  hipMemsetAsync(deg, 0, N * sizeof(int), stream);
  detect_i64<<<1, 64, 0, stream>>>(edges, flag);
  int eb = (int)((E + 255) / 256);
  norm_edges<<<eb, 256, 0, stream>>>(edges, flag, s32, d32);
  count_deg<<<eb, 256, 0, stream>>>(d32, deg);
  int nb = (int)((N + 255) / 256);  // 196
  scan_bsum<<<nb, 256, 0, stream>>>(deg, bsums);
  scan_offsets<<<1, 256, 0, stream>>>(bsums, rowp, nb);
  scan_final<<<nb, 256, 0, stream>>>(deg, bsums, rowp, cursor);
  scatter_edges<<<eb, 256, 0, stream>>>(s32, d32, cursor, srcs);

  dim3 g1((unsigned)((N + 63) / 64), 4);
  dim3 g3((unsigned)((N + 63) / 64), 1);

  // layer 1
  gemm_k256<<<g1, 256, 0, stream>>>(x, W1, h, 256);
  elr_heads<<<(unsigned)N, 256, 0, stream>>>(h, al1, ar1, el, er);
  agg_heads<<<(unsigned)N, 256, 0, stream>>>(h, el, er, b1, rowp, srcs, o);
  // layer 2
  gemm_k256<<<g1, 256, 0, stream>>>(o, W2, h, 256);
  elr_heads<<<(unsigned)N, 256, 0, stream>>>(h, al2, ar2, el, er);
  agg_heads<<<(unsigned)N, 256, 0, stream>>>(h, el, er, b2, rowp, srcs, o);
  // layer 3 + fused log_softmax
  gemm_k256<<<g3, 256, 0, stream>>>(o, W3, h3, 40);
  elr_cls<<<(unsigned)N, 64, 0, stream>>>(h3, al3, ar3, el, er);
  agg_cls<<<(unsigned)N, 64, 0, stream>>>(h3, el, er, b3, rowp, srcs, out);
}

// Round 3
// 798.827 us; speedup vs baseline: 1.1575x; 1.1575x over previous
//
#include <hip/hip_runtime.h>
#include <hip/hip_bf16.h>
#include <math.h>

#define N_NODES 50000
#define N_EDGES 800000
#define NCLASS 40

// ---------------- edge dtype normalize ----------------
__global__ void detect_i64(const int* __restrict__ raw, int* __restrict__ flag) {
  int t = threadIdx.x;
  int v = raw[2 * t + 1];
  unsigned long long any = __ballot(v != 0);
  if (t == 0) flag[0] = (any == 0ULL) ? 1 : 0;
}

__global__ void norm_edges(const int* __restrict__ raw, const int* __restrict__ flag,
                           int* __restrict__ s32, int* __restrict__ d32) {
  int e = blockIdx.x * blockDim.x + threadIdx.x;
  if (e >= N_EDGES) return;
  if (flag[0]) {
    s32[e] = raw[2 * e];
    d32[e] = raw[2 * N_EDGES + 2 * e];
  } else {
    s32[e] = raw[e];
    d32[e] = raw[N_EDGES + e];
  }
}

// ---------------- CSR build (group edges by dst) ----------------
__global__ void count_deg(const int* __restrict__ d32, int* __restrict__ deg) {
  int e = blockIdx.x * blockDim.x + threadIdx.x;
  if (e < N_EDGES) atomicAdd(&deg[d32[e]], 1);
}

__global__ void scan_bsum(const int* __restrict__ deg, int* __restrict__ bsums) {
  __shared__ int sm[256];
  int t = threadIdx.x;
  int i = blockIdx.x * 256 + t;
  sm[t] = (i < N_NODES) ? deg[i] : 0;
  __syncthreads();
  for (int off = 128; off > 0; off >>= 1) {
    if (t < off) sm[t] += sm[t + off];
    __syncthreads();
  }
  if (t == 0) bsums[blockIdx.x] = sm[0];
}

__global__ void scan_offsets(int* __restrict__ bsums, int* __restrict__ rowp, int nb) {
  __shared__ int sm[256];
  int t = threadIdx.x;
  int v = (t < nb) ? bsums[t] : 0;
  sm[t] = v;
  __syncthreads();
  for (int off = 1; off < 256; off <<= 1) {
    int add = (t >= off) ? sm[t - off] : 0;
    __syncthreads();
    sm[t] += add;
    __syncthreads();
  }
  if (t < nb) bsums[t] = sm[t] - v;
  if (t == 0) rowp[N_NODES] = N_EDGES;
}

__global__ void scan_final(const int* __restrict__ deg, const int* __restrict__ bsums,
                           int* __restrict__ rowp, int* __restrict__ cursor) {
  __shared__ int sm[256];
  int t = threadIdx.x;
  int i = blockIdx.x * 256 + t;
  int v = (i < N_NODES) ? deg[i] : 0;
  sm[t] = v;
  __syncthreads();
  for (int off = 1; off < 256; off <<= 1) {
    int add = (t >= off) ? sm[t - off] : 0;
    __syncthreads();
    sm[t] += add;
    __syncthreads();
  }
  int excl = sm[t] - v + bsums[blockIdx.x];
  if (i < N_NODES) { rowp[i] = excl; cursor[i] = excl; }
}

__global__ void scatter_edges(const int* __restrict__ s32, const int* __restrict__ d32,
                              int* __restrict__ cursor, int* __restrict__ srcs) {
  int e = blockIdx.x * blockDim.x + threadIdx.x;
  if (e >= N_EDGES) return;
  int d = d32[e];
  int pos = atomicAdd(&cursor[d], 1);
  srcs[pos] = s32[e];
}

// ---------------- fp32 tiled GEMM: C[N,Mout] = A[N,256] @ W[256,Mout] ----------------
__global__ __launch_bounds__(256) void gemm_k256(const float* __restrict__ A,
                                                 const float* __restrict__ W,
                                                 float* __restrict__ C, int Mout) {
  __shared__ float As[16][68];
  __shared__ float Bs[16][68];
  int t = threadIdx.x;
  int tx = t & 15, ty = t >> 4;
  int row0 = blockIdx.x * 64, col0 = blockIdx.y * 64;
  int a_r = t >> 2, a_k = (t & 3) << 2;
  int b_k = t >> 4, b_n = (t & 15) << 2;
  float acc[4][4] = {};
  for (int k0 = 0; k0 < 256; k0 += 16) {
    float4 av = make_float4(0.f, 0.f, 0.f, 0.f);
    int grow = row0 + a_r;
    if (grow < N_NODES)
      av = *reinterpret_cast<const float4*>(A + (size_t)grow * 256 + k0 + a_k);
    As[a_k + 0][a_r] = av.x;
    As[a_k + 1][a_r] = av.y;
    As[a_k + 2][a_r] = av.z;
    As[a_k + 3][a_r] = av.w;
    float4 bv = make_float4(0.f, 0.f, 0.f, 0.f);
    int gcol = col0 + b_n;
    if (gcol < Mout)
      bv = *reinterpret_cast<const float4*>(W + (size_t)(k0 + b_k) * Mout + gcol);
    *reinterpret_cast<float4*>(&Bs[b_k][b_n]) = bv;
    __syncthreads();
#pragma unroll
    for (int k = 0; k < 16; ++k) {
      float4 a = *reinterpret_cast<const float4*>(&As[k][ty * 4]);
      float4 b = *reinterpret_cast<const float4*>(&Bs[k][tx * 4]);
      acc[0][0] += a.x * b.x; acc[0][1] += a.x * b.y; acc[0][2] += a.x * b.z; acc[0][3] += a.x * b.w;
      acc[1][0] += a.y * b.x; acc[1][1] += a.y * b.y; acc[1][2] += a.y * b.z; acc[1][3] += a.y * b.w;
      acc[2][0] += a.z * b.x; acc[2][1] += a.z * b.y; acc[2][2] += a.z * b.z; acc[2][3] += a.z * b.w;
      acc[3][0] += a.w * b.x; acc[3][1] += a.w * b.y; acc[3][2] += a.w * b.z; acc[3][3] += a.w * b.w;
    }
    __syncthreads();
  }
  int c = col0 + tx * 4;
  if (c + 3 < Mout) {
#pragma unroll
    for (int i = 0; i < 4; ++i) {
      int r = row0 + ty * 4 + i;
      if (r < N_NODES) {
        float4 v = make_float4(acc[i][0], acc[i][1], acc[i][2], acc[i][3]);
        *reinterpret_cast<float4*>(C + (size_t)r * Mout + c) = v;
      }
    }
  }
}

// ---------------- el/er dots + bf16 copy of h ----------------
__global__ __launch_bounds__(256) void elr_heads(const float* __restrict__ h,
                                                 const float* __restrict__ al,
                                                 const float* __restrict__ ar,
                                                 float* __restrict__ el, float* __restrict__ er,
                                                 __hip_bfloat16* __restrict__ hb) {
  int n = blockIdx.x, t = threadIdx.x;  // t = head*64 + d
  float hv = h[(size_t)n * 256 + t];
  hb[(size_t)n * 256 + t] = __float2bfloat16(hv);
  float pl = hv * al[t];
  float pr = hv * ar[t];
  for (int off = 32; off > 0; off >>= 1) {
    pl += __shfl_down(pl, off);
    pr += __shfl_down(pr, off);
  }
  if ((t & 63) == 0) {
    el[n * 4 + (t >> 6)] = pl;
    er[n * 4 + (t >> 6)] = pr;
  }
}

__global__ __launch_bounds__(64) void elr_cls(const float* __restrict__ h3,
                                              const float* __restrict__ al,
                                              const float* __restrict__ ar,
                                              float* __restrict__ el, float* __restrict__ er) {
  int n = blockIdx.x, t = threadIdx.x;
  bool act = t < NCLASS;
  float hv = act ? h3[(size_t)n * NCLASS + t] : 0.f;
  float pl = act ? hv * al[t] : 0.f;
  float pr = act ? hv * ar[t] : 0.f;
  for (int off = 32; off > 0; off >>= 1) {
    pl += __shfl_down(pl, off);
    pr += __shfl_down(pr, off);
  }
  if (t == 0) { el[n] = pl; er[n] = pr; }
}

// ---------------- normalized edge weights (per dst node, 4 heads) ----------------
// One wave per node. lane = slot*4 + head; 16 edge-slots x 4 heads.
__global__ __launch_bounds__(64) void alpha_heads(const float* __restrict__ el,
                                                  const float* __restrict__ er,
                                                  const int* __restrict__ rowp,
                                                  const int* __restrict__ srcs,
                                                  float* __restrict__ alpha) {
  int n = blockIdx.x;
  int lane = threadIdx.x;
  int head = lane & 3, slot = lane >> 2;
  int i0 = rowp[n], i1 = rowp[n + 1];
  float ern = er[n * 4 + head];
  float m = -1e30f, l = 0.f;
  for (int base = i0; base < i1; base += 16) {
    int i = base + slot;
    float e = -1e30f;
    if (i < i1) {
      int s = srcs[i];
      e = el[s * 4 + head] + ern;
      e = (e >= 0.f) ? e : 0.2f * e;
    }
    float nm = fmaxf(m, e);
    l = l * __expf(m - nm) + ((i < i1) ? __expf(e - nm) : 0.f);
    m = nm;
  }
  // butterfly-combine the 16 slots of each head (lanes differ in bits 2..5)
  for (int off = 4; off <= 32; off <<= 1) {
    float mo = __shfl_xor(m, off);
    float lo = __shfl_xor(l, off);
    float nm = fmaxf(m, mo);
    l = l * __expf(m - nm) + lo * __expf(mo - nm);
    m = nm;
  }
  float inv = (l > 0.f) ? (1.f / l) : 0.f;
  for (int base = i0; base < i1; base += 16) {
    int i = base + slot;
    if (i < i1) {
      int s = srcs[i];
      float e = el[s * 4 + head] + ern;
      e = (e >= 0.f) ? e : 0.2f * e;
      alpha[(size_t)i * 4 + head] = __expf(e - m) * inv;  // contiguous per lane
    }
  }
}

// one wave per node, single head (layer 3)
__global__ __launch_bounds__(64) void alpha_cls(const float* __restrict__ el,
                                                const float* __restrict__ er,
                                                const int* __restrict__ rowp,
                                                const int* __restrict__ srcs,
                                                float* __restrict__ alpha) {
  int n = blockIdx.x;
  int slot = threadIdx.x;
  int i0 = rowp[n], i1 = rowp[n + 1];
  float ern = er[n];
  float m = -1e30f, l = 0.f;
  for (int base = i0; base < i1; base += 64) {
    int i = base + slot;
    float e = -1e30f;
    if (i < i1) {
      int s = srcs[i];
      e = el[s] + ern;
      e = (e >= 0.f) ? e : 0.2f * e;
    }
    float nm = fmaxf(m, e);
    l = l * __expf(m - nm) + ((i < i1) ? __expf(e - nm) : 0.f);
    m = nm;
  }
  for (int off = 1; off <= 32; off <<= 1) {
    float mo = __shfl_xor(m, off);
    float lo = __shfl_xor(l, off);
    float nm = fmaxf(m, mo);
    l = l * __expf(m - nm) + lo * __expf(mo - nm);
    m = nm;
  }
  float inv = (l > 0.f) ? (1.f / l) : 0.f;
  for (int base = i0; base < i1; base += 64) {
    int i = base + slot;
    if (i < i1) {
      int s = srcs[i];
      float e = el[s] + ern;
      e = (e >= 0.f) ? e : 0.2f * e;
      alpha[i] = __expf(e - m) * inv;
    }
  }
}

// ---------------- weighted gather (+bias+ELU) ----------------
__global__ __launch_bounds__(256) void agg_gather(const __hip_bfloat16* __restrict__ hb,
                                                  const float* __restrict__ alpha,
                                                  const float* __restrict__ bias,
                                                  const int* __restrict__ rowp,
                                                  const int* __restrict__ srcs,
                                                  float* __restrict__ o) {
  int n = blockIdx.x, t = threadIdx.x;  // t = head*64 + d
  int head = t >> 6;
  int i0 = rowp[n], i1 = rowp[n + 1];
  float acc0 = 0.f, acc1 = 0.f;
  int i = i0;
  for (; i + 1 < i1; i += 2) {
    int s0 = srcs[i], s1 = srcs[i + 1];
    float a0 = alpha[(size_t)i * 4 + head];
    float a1 = alpha[(size_t)(i + 1) * 4 + head];
    float h0 = __bfloat162float(hb[(size_t)s0 * 256 + t]);
    float h1 = __bfloat162float(hb[(size_t)s1 * 256 + t]);
    acc0 += a0 * h0;
    acc1 += a1 * h1;
  }
  if (i < i1) {
    int s0 = srcs[i];
    acc0 += alpha[(size_t)i * 4 + head] * __bfloat162float(hb[(size_t)s0 * 256 + t]);
  }
  float v = acc0 + acc1 + bias[t];
  v = (v > 0.f) ? v : (__expf(v) - 1.f);  // ELU
  o[(size_t)n * 256 + t] = v;
}

// layer 3 gather + bias + fused log_softmax (h3 fp32, 1 head)
__global__ __launch_bounds__(64) void agg_cls(const float* __restrict__ h3,
                                              const float* __restrict__ alpha,
                                              const float* __restrict__ bias,
                                              const int* __restrict__ rowp,
                                              const int* __restrict__ srcs,
                                              float* __restrict__ out) {
  int n = blockIdx.x, t = threadIdx.x;
  bool act = t < NCLASS;
  int i0 = rowp[n], i1 = rowp[n + 1];
  float acc0 = 0.f, acc1 = 0.f;
  int i = i0;
  for (; i + 1 < i1; i += 2) {
    int s0 = srcs[i], s1 = srcs[i + 1];
    float a0 = alpha[i], a1 = alpha[i + 1];
    if (act) {
      acc0 += a0 * h3[(size_t)s0 * NCLASS + t];
      acc1 += a1 * h3[(size_t)s1 * NCLASS + t];
    }
  }
  if (i < i1 && act) acc0 += alpha[i] * h3[(size_t)srcs[i] * NCLASS + t];
  float z = acc0 + acc1 + (act ? bias[t] : 0.f);
  float zz = act ? z : -INFINITY;
  float mx = zz;
  for (int off = 32; off > 0; off >>= 1) mx = fmaxf(mx, __shfl_xor(mx, off));
  float ex = act ? __expf(z - mx) : 0.f;
  float sum = ex;
  for (int off = 32; off > 0; off >>= 1) sum += __shfl_xor(sum, off);
  if (act) out[(size_t)n * NCLASS + t] = z - mx - __logf(sum);
}

extern "C" void kernel_launch(void* const* d_in, const int* in_sizes, int n_in,
                              void* d_out, int out_size, void* d_ws, size_t ws_size,
                              hipStream_t stream) {
  const float* x   = (const float*)d_in[0];
  const int* edges = (const int*)d_in[1];
  const float* W1  = (const float*)d_in[2];
  const float* al1 = (const float*)d_in[3];
  const float* ar1 = (const float*)d_in[4];
  const float* b1  = (const float*)d_in[5];
  const float* W2  = (const float*)d_in[6];
  const float* al2 = (const float*)d_in[7];
  const float* ar2 = (const float*)d_in[8];
  const float* b2  = (const float*)d_in[9];
  const float* W3  = (const float*)d_in[10];
  const float* al3 = (const float*)d_in[11];
  const float* ar3 = (const float*)d_in[12];
  const float* b3  = (const float*)d_in[13];
  float* out = (float*)d_out;

  const size_t N = N_NODES, E = N_EDGES;
  float* h  = (float*)d_ws;            // [N,256]
  float* o  = h + N * 256;             // [N,256]
  float* h3 = o + N * 256;             // [N,40]
  float* el = h3 + N * 40;             // [N,4]
  float* er = el + N * 4;              // [N,4]
  float* alpha = er + N * 4;           // [E,4]
  __hip_bfloat16* hb = (__hip_bfloat16*)(alpha + E * 4);  // [N,256] bf16
  int* rowp   = (int*)(hb + N * 256);  // [N+1]
  int* cursor = rowp + (N + 1);        // [N]
  int* srcs   = cursor + N;            // [E]
  int* deg    = srcs + E;              // [N]
  int* bsums  = deg + N;               // [256]
  int* s32    = bsums + 256;           // [E]
  int* d32    = s32 + E;               // [E]
  int* flag   = d32 + E;               // [1]
  float* alpha3 = (float*)s32;         // [E] — s32 dead after scatter_edges

  hipMemsetAsync(deg, 0, N * sizeof(int), stream);
  detect_i64<<<1, 64, 0, stream>>>(edges, flag);
  int eb = (int)((E + 255) / 256);
  norm_edges<<<eb, 256, 0, stream>>>(edges, flag, s32, d32);
  count_deg<<<eb, 256, 0, stream>>>(d32, deg);
  int nb = (int)((N + 255) / 256);
  scan_bsum<<<nb, 256, 0, stream>>>(deg, bsums);
  scan_offsets<<<1, 256, 0, stream>>>(bsums, rowp, nb);
  scan_final<<<nb, 256, 0, stream>>>(deg, bsums, rowp, cursor);
  scatter_edges<<<eb, 256, 0, stream>>>(s32, d32, cursor, srcs);

  dim3 g1((unsigned)((N + 63) / 64), 4);
  dim3 g3((unsigned)((N + 63) / 64), 1);

  // layer 1
  gemm_k256<<<g1, 256, 0, stream>>>(x, W1, h, 256);
  elr_heads<<<(unsigned)N, 256, 0, stream>>>(h, al1, ar1, el, er, hb);
  alpha_heads<<<(unsigned)N, 64, 0, stream>>>(el, er, rowp, srcs, alpha);
  agg_gather<<<(unsigned)N, 256, 0, stream>>>(hb, alpha, b1, rowp, srcs, o);
  // layer 2
  gemm_k256<<<g1, 256, 0, stream>>>(o, W2, h, 256);
  elr_heads<<<(unsigned)N, 256, 0, stream>>>(h, al2, ar2, el, er, hb);
  alpha_heads<<<(unsigned)N, 64, 0, stream>>>(el, er, rowp, srcs, alpha);
  agg_gather<<<(unsigned)N, 256, 0, stream>>>(hb, alpha, b2, rowp, srcs, o);
  // layer 3 + fused log_softmax
  gemm_k256<<<g3, 256, 0, stream>>>(o, W3, h3, 40);
  elr_cls<<<(unsigned)N, 64, 0, stream>>>(h3, al3, ar3, el, er);
  alpha_cls<<<(unsigned)N, 64, 0, stream>>>(el, er, rowp, srcs, alpha3);
  agg_cls<<<(unsigned)N, 64, 0, stream>>>(h3, alpha3, b3, rowp, srcs, out);
}

// Round 4
// 671.058 us; speedup vs baseline: 1.3778x; 1.1904x over previous
//
#include <hip/hip_runtime.h>
#include <hip/hip_bf16.h>
#include <math.h>

#define N_NODES 50000
#define N_EDGES 800000
#define NCLASS 40

using f32x4 = __attribute__((ext_vector_type(4))) float;
using s16x8 = __attribute__((ext_vector_type(8))) short;

// ---------------- edge dtype normalize ----------------
__global__ void detect_i64(const int* __restrict__ raw, int* __restrict__ flag) {
  int t = threadIdx.x;
  int v = raw[2 * t + 1];
  unsigned long long any = __ballot(v != 0);
  if (t == 0) flag[0] = (any == 0ULL) ? 1 : 0;
}

__global__ void norm_edges(const int* __restrict__ raw, const int* __restrict__ flag,
                           int* __restrict__ s32, int* __restrict__ d32) {
  int e = blockIdx.x * blockDim.x + threadIdx.x;
  if (e >= N_EDGES) return;
  if (flag[0]) {
    s32[e] = raw[2 * e];
    d32[e] = raw[2 * N_EDGES + 2 * e];
  } else {
    s32[e] = raw[e];
    d32[e] = raw[N_EDGES + e];
  }
}

// ---------------- CSR build (group edges by dst) ----------------
__global__ void count_deg(const int* __restrict__ d32, int* __restrict__ deg) {
  int e = blockIdx.x * blockDim.x + threadIdx.x;
  if (e < N_EDGES) atomicAdd(&deg[d32[e]], 1);
}

__global__ void scan_bsum(const int* __restrict__ deg, int* __restrict__ bsums) {
  __shared__ int sm[256];
  int t = threadIdx.x;
  int i = blockIdx.x * 256 + t;
  sm[t] = (i < N_NODES) ? deg[i] : 0;
  __syncthreads();
  for (int off = 128; off > 0; off >>= 1) {
    if (t < off) sm[t] += sm[t + off];
    __syncthreads();
  }
  if (t == 0) bsums[blockIdx.x] = sm[0];
}

__global__ void scan_offsets(int* __restrict__ bsums, int* __restrict__ rowp, int nb) {
  __shared__ int sm[256];
  int t = threadIdx.x;
  int v = (t < nb) ? bsums[t] : 0;
  sm[t] = v;
  __syncthreads();
  for (int off = 1; off < 256; off <<= 1) {
    int add = (t >= off) ? sm[t - off] : 0;
    __syncthreads();
    sm[t] += add;
    __syncthreads();
  }
  if (t < nb) bsums[t] = sm[t] - v;
  if (t == 0) rowp[N_NODES] = N_EDGES;
}

__global__ void scan_final(const int* __restrict__ deg, const int* __restrict__ bsums,
                           int* __restrict__ rowp, int* __restrict__ cursor) {
  __shared__ int sm[256];
  int t = threadIdx.x;
  int i = blockIdx.x * 256 + t;
  int v = (i < N_NODES) ? deg[i] : 0;
  sm[t] = v;
  __syncthreads();
  for (int off = 1; off < 256; off <<= 1) {
    int add = (t >= off) ? sm[t - off] : 0;
    __syncthreads();
    sm[t] += add;
    __syncthreads();
  }
  int excl = sm[t] - v + bsums[blockIdx.x];
  if (i < N_NODES) { rowp[i] = excl; cursor[i] = excl; }
}

__global__ void scatter_edges(const int* __restrict__ s32, const int* __restrict__ d32,
                              int* __restrict__ cursor, int* __restrict__ srcs) {
  int e = blockIdx.x * blockDim.x + threadIdx.x;
  if (e >= N_EDGES) return;
  int d = d32[e];
  int pos = atomicAdd(&cursor[d], 1);
  srcs[pos] = s32[e];
}

// ---------------- weight prep: WT[n][k] = bf16(W[k][n]) ----------------
__global__ void tr_w(const float* __restrict__ W, __hip_bfloat16* __restrict__ WT) {
  int id = blockIdx.x * 256 + threadIdx.x;  // 65536
  int n = id >> 8, k = id & 255;
  WT[n * 256 + k] = __float2bfloat16(W[k * 256 + n]);
}

// W3 [256][40] -> WT3 [64][256] zero-padded
__global__ void tr_w3(const float* __restrict__ W3, __hip_bfloat16* __restrict__ WT3) {
  int id = blockIdx.x * 256 + threadIdx.x;  // 16384
  int n = id >> 8, k = id & 255;
  WT3[n * 256 + k] = (n < NCLASS) ? __float2bfloat16(W3[k * NCLASS + n]) : __float2bfloat16(0.f);
}

__global__ void cast_x(const float* __restrict__ x, __hip_bfloat16* __restrict__ xb) {
  int id = blockIdx.x * 256 + threadIdx.x;  // N*256/4 threads
  float4 v = *reinterpret_cast<const float4*>(x + (size_t)id * 4);
  ushort4 u;
  __hip_bfloat16 b;
  b = __float2bfloat16(v.x); u.x = *(unsigned short*)&b;
  b = __float2bfloat16(v.y); u.y = *(unsigned short*)&b;
  b = __float2bfloat16(v.z); u.z = *(unsigned short*)&b;
  b = __float2bfloat16(v.w); u.w = *(unsigned short*)&b;
  *reinterpret_cast<ushort4*>((unsigned short*)xb + (size_t)id * 4) = u;
}

// ---------------- bf16 MFMA GEMM: C[rows,ldc] = A[rows,256] @ WT^T ----------------
// A row-major bf16 (lda=256); WT row-major bf16 [ncols][256] (pre-transposed W).
// BM=128, BK=32. BN=128: 4 waves as 2x2, wave tile 64x64. BN=64: 4 waves as 4x1, wave tile 32x64.
template <int BN>
__global__ __launch_bounds__(256) void gemm_mfma(const __hip_bfloat16* __restrict__ A,
                                                 const __hip_bfloat16* __restrict__ WT,
                                                 float* __restrict__ C, int ldc) {
  constexpr int WCOLS = (BN == 128) ? 2 : 1;
  constexpr int WROWS = 4 / WCOLS;
  constexpr int MREP = 128 / (16 * WROWS);  // 4 or 2
  constexpr int NREP = 4;
  __shared__ __align__(16) __hip_bfloat16 As[128][40];
  __shared__ __align__(16) __hip_bfloat16 Bs[BN][40];

  int t = threadIdx.x;
  int lane = t & 63, wave = t >> 6;
  int wr = wave / WCOLS, wc = wave % WCOLS;
  int row0 = blockIdx.x * 128, col0 = blockIdx.y * BN;
  int ln = lane & 15;
  int kc8 = (lane >> 4) * 8;

  f32x4 acc[MREP][NREP];
  const f32x4 fz = {0.f, 0.f, 0.f, 0.f};
#pragma unroll
  for (int m = 0; m < MREP; ++m)
#pragma unroll
    for (int n = 0; n < NREP; ++n) acc[m][n] = fz;

  const f32x4 zero16 = {0.f, 0.f, 0.f, 0.f};
  for (int k0 = 0; k0 < 256; k0 += 32) {
    // stage A tile: 128 rows x 32 k, 512 16B-chunks
#pragma unroll
    for (int it = 0; it < 2; ++it) {
      int c = t + it * 256;
      int r = c >> 2, kc = (c & 3) * 8;
      int grow = row0 + r;
      f32x4 v = zero16;
      if (grow < N_NODES)
        v = *reinterpret_cast<const f32x4*>(A + (size_t)grow * 256 + k0 + kc);
      *reinterpret_cast<f32x4*>(&As[r][kc]) = v;
    }
    // stage B tile: BN rows x 32 k
#pragma unroll
    for (int it = 0; it < BN / 64; ++it) {
      int c = t + it * 256;
      int r = c >> 2, kc = (c & 3) * 8;
      f32x4 v = *reinterpret_cast<const f32x4*>(WT + (size_t)(col0 + r) * 256 + k0 + kc);
      *reinterpret_cast<f32x4*>(&Bs[r][kc]) = v;
    }
    __syncthreads();
    s16x8 af[MREP], bfr[NREP];
#pragma unroll
    for (int m = 0; m < MREP; ++m)
      af[m] = *reinterpret_cast<const s16x8*>(&As[wr * (MREP * 16) + m * 16 + ln][kc8]);
#pragma unroll
    for (int n = 0; n < NREP; ++n)
      bfr[n] = *reinterpret_cast<const s16x8*>(&Bs[wc * 64 + n * 16 + ln][kc8]);
#pragma unroll
    for (int m = 0; m < MREP; ++m)
#pragma unroll
      for (int n = 0; n < NREP; ++n)
        acc[m][n] = __builtin_amdgcn_mfma_f32_16x16x32_bf16(af[m], bfr[n], acc[m][n], 0, 0, 0);
    __syncthreads();
  }
  // epilogue: C/D layout col=lane&15, row=(lane>>4)*4+reg
#pragma unroll
  for (int m = 0; m < MREP; ++m) {
    int rowb = row0 + wr * (MREP * 16) + m * 16 + (lane >> 4) * 4;
#pragma unroll
    for (int n = 0; n < NREP; ++n) {
      int col = col0 + wc * 64 + n * 16 + ln;
#pragma unroll
      for (int r = 0; r < 4; ++r) {
        int row = rowb + r;
        if (row < N_NODES) C[(size_t)row * ldc + col] = acc[m][n][r];
      }
    }
  }
}

// ---------------- el/er dots + bf16 copy of h ----------------
__global__ __launch_bounds__(256) void elr_heads(const float* __restrict__ h,
                                                 const float* __restrict__ al,
                                                 const float* __restrict__ ar,
                                                 float* __restrict__ el, float* __restrict__ er,
                                                 __hip_bfloat16* __restrict__ hb) {
  int n = blockIdx.x, t = threadIdx.x;  // t = head*64 + d
  float hv = h[(size_t)n * 256 + t];
  hb[(size_t)n * 256 + t] = __float2bfloat16(hv);
  float pl = hv * al[t];
  float pr = hv * ar[t];
  for (int off = 32; off > 0; off >>= 1) {
    pl += __shfl_down(pl, off);
    pr += __shfl_down(pr, off);
  }
  if ((t & 63) == 0) {
    el[n * 4 + (t >> 6)] = pl;
    er[n * 4 + (t >> 6)] = pr;
  }
}

__global__ __launch_bounds__(64) void elr_cls(const float* __restrict__ h3,
                                              const float* __restrict__ al,
                                              const float* __restrict__ ar,
                                              float* __restrict__ el, float* __restrict__ er) {
  int n = blockIdx.x, t = threadIdx.x;
  bool act = t < NCLASS;
  float hv = act ? h3[(size_t)n * 64 + t] : 0.f;
  float pl = act ? hv * al[t] : 0.f;
  float pr = act ? hv * ar[t] : 0.f;
  for (int off = 32; off > 0; off >>= 1) {
    pl += __shfl_down(pl, off);
    pr += __shfl_down(pr, off);
  }
  if (t == 0) { el[n] = pl; er[n] = pr; }
}

// ---------------- normalized edge weights ----------------
__global__ __launch_bounds__(64) void alpha_heads(const float* __restrict__ el,
                                                  const float* __restrict__ er,
                                                  const int* __restrict__ rowp,
                                                  const int* __restrict__ srcs,
                                                  float* __restrict__ alpha) {
  int n = blockIdx.x;
  int lane = threadIdx.x;
  int head = lane & 3, slot = lane >> 2;
  int i0 = rowp[n], i1 = rowp[n + 1];
  float ern = er[n * 4 + head];
  float m = -1e30f, l = 0.f;
  for (int base = i0; base < i1; base += 16) {
    int i = base + slot;
    float e = -1e30f;
    if (i < i1) {
      int s = srcs[i];
      e = el[s * 4 + head] + ern;
      e = (e >= 0.f) ? e : 0.2f * e;
    }
    float nm = fmaxf(m, e);
    l = l * __expf(m - nm) + ((i < i1) ? __expf(e - nm) : 0.f);
    m = nm;
  }
  for (int off = 4; off <= 32; off <<= 1) {
    float mo = __shfl_xor(m, off);
    float lo = __shfl_xor(l, off);
    float nm = fmaxf(m, mo);
    l = l * __expf(m - nm) + lo * __expf(mo - nm);
    m = nm;
  }
  float inv = (l > 0.f) ? (1.f / l) : 0.f;
  for (int base = i0; base < i1; base += 16) {
    int i = base + slot;
    if (i < i1) {
      int s = srcs[i];
      float e = el[s * 4 + head] + ern;
      e = (e >= 0.f) ? e : 0.2f * e;
      alpha[(size_t)i * 4 + head] = __expf(e - m) * inv;
    }
  }
}

__global__ __launch_bounds__(64) void alpha_cls(const float* __restrict__ el,
                                                const float* __restrict__ er,
                                                const int* __restrict__ rowp,
                                                const int* __restrict__ srcs,
                                                float* __restrict__ alpha) {
  int n = blockIdx.x;
  int slot = threadIdx.x;
  int i0 = rowp[n], i1 = rowp[n + 1];
  float ern = er[n];
  float m = -1e30f, l = 0.f;
  for (int base = i0; base < i1; base += 64) {
    int i = base + slot;
    float e = -1e30f;
    if (i < i1) {
      int s = srcs[i];
      e = el[s] + ern;
      e = (e >= 0.f) ? e : 0.2f * e;
    }
    float nm = fmaxf(m, e);
    l = l * __expf(m - nm) + ((i < i1) ? __expf(e - nm) : 0.f);
    m = nm;
  }
  for (int off = 1; off <= 32; off <<= 1) {
    float mo = __shfl_xor(m, off);
    float lo = __shfl_xor(l, off);
    float nm = fmaxf(m, mo);
    l = l * __expf(m - nm) + lo * __expf(mo - nm);
    m = nm;
  }
  float inv = (l > 0.f) ? (1.f / l) : 0.f;
  for (int base = i0; base < i1; base += 64) {
    int i = base + slot;
    if (i < i1) {
      int s = srcs[i];
      float e = el[s] + ern;
      e = (e >= 0.f) ? e : 0.2f * e;
      alpha[i] = __expf(e - m) * inv;
    }
  }
}

// ---------------- weighted gather (+bias+ELU) -> bf16 out ----------------
__global__ __launch_bounds__(256) void agg_gather(const __hip_bfloat16* __restrict__ hb,
                                                  const float* __restrict__ alpha,
                                                  const float* __restrict__ bias,
                                                  const int* __restrict__ rowp,
                                                  const int* __restrict__ srcs,
                                                  __hip_bfloat16* __restrict__ ob) {
  int n = blockIdx.x, t = threadIdx.x;  // t = head*64 + d
  int head = t >> 6;
  int i0 = rowp[n], i1 = rowp[n + 1];
  float acc0 = 0.f, acc1 = 0.f;
  int i = i0;
  for (; i + 1 < i1; i += 2) {
    int s0 = srcs[i], s1 = srcs[i + 1];
    float a0 = alpha[(size_t)i * 4 + head];
    float a1 = alpha[(size_t)(i + 1) * 4 + head];
    float h0 = __bfloat162float(hb[(size_t)s0 * 256 + t]);
    float h1 = __bfloat162float(hb[(size_t)s1 * 256 + t]);
    acc0 += a0 * h0;
    acc1 += a1 * h1;
  }
  if (i < i1) {
    int s0 = srcs[i];
    acc0 += alpha[(size_t)i * 4 + head] * __bfloat162float(hb[(size_t)s0 * 256 + t]);
  }
  float v = acc0 + acc1 + bias[t];
  v = (v > 0.f) ? v : (__expf(v) - 1.f);  // ELU
  ob[(size_t)n * 256 + t] = __float2bfloat16(v);
}

// layer 3 gather + bias + fused log_softmax (h3 fp32 [N,64], 1 head)
__global__ __launch_bounds__(64) void agg_cls(const float* __restrict__ h3,
                                              const float* __restrict__ alpha,
                                              const float* __restrict__ bias,
                                              const int* __restrict__ rowp,
                                              const int* __restrict__ srcs,
                                              float* __restrict__ out) {
  int n = blockIdx.x, t = threadIdx.x;
  bool act = t < NCLASS;
  int i0 = rowp[n], i1 = rowp[n + 1];
  float acc0 = 0.f, acc1 = 0.f;
  int i = i0;
  for (; i + 1 < i1; i += 2) {
    int s0 = srcs[i], s1 = srcs[i + 1];
    float a0 = alpha[i], a1 = alpha[i + 1];
    if (act) {
      acc0 += a0 * h3[(size_t)s0 * 64 + t];
      acc1 += a1 * h3[(size_t)s1 * 64 + t];
    }
  }
  if (i < i1 && act) acc0 += alpha[i] * h3[(size_t)srcs[i] * 64 + t];
  float z = acc0 + acc1 + (act ? bias[t] : 0.f);
  float zz = act ? z : -INFINITY;
  float mx = zz;
  for (int off = 32; off > 0; off >>= 1) mx = fmaxf(mx, __shfl_xor(mx, off));
  float ex = act ? __expf(z - mx) : 0.f;
  float sum = ex;
  for (int off = 32; off > 0; off >>= 1) sum += __shfl_xor(sum, off);
  if (act) out[(size_t)n * NCLASS + t] = z - mx - __logf(sum);
}

extern "C" void kernel_launch(void* const* d_in, const int* in_sizes, int n_in,
                              void* d_out, int out_size, void* d_ws, size_t ws_size,
                              hipStream_t stream) {
  const float* x   = (const float*)d_in[0];
  const int* edges = (const int*)d_in[1];
  const float* W1  = (const float*)d_in[2];
  const float* al1 = (const float*)d_in[3];
  const float* ar1 = (const float*)d_in[4];
  const float* b1  = (const float*)d_in[5];
  const float* W2  = (const float*)d_in[6];
  const float* al2 = (const float*)d_in[7];
  const float* ar2 = (const float*)d_in[8];
  const float* b2  = (const float*)d_in[9];
  const float* W3  = (const float*)d_in[10];
  const float* al3 = (const float*)d_in[11];
  const float* ar3 = (const float*)d_in[12];
  const float* b3  = (const float*)d_in[13];
  float* out = (float*)d_out;

  const size_t N = N_NODES, E = N_EDGES;
  float* h  = (float*)d_ws;              // [N,256] fp32
  float* h3 = h + N * 256;               // [N,64] fp32
  float* el = h3 + N * 64;               // [N,4]
  float* er = el + N * 4;                // [N,4]
  float* alpha = er + N * 4;             // [E,4]
  __hip_bfloat16* hb = (__hip_bfloat16*)(alpha + E * 4);  // [N,256]
  __hip_bfloat16* ob = hb + N * 256;     // [N,256]
  __hip_bfloat16* WT = ob + N * 256;     // [256,256]
  __hip_bfloat16* WT3 = WT + 256 * 256;  // [64,256]
  int* rowp   = (int*)(WT3 + 64 * 256);  // [N+1]
  int* cursor = rowp + (N + 1);          // [N]
  int* srcs   = cursor + N;              // [E]
  int* deg    = srcs + E;                // [N]
  int* bsums  = deg + N;                 // [256]
  int* s32    = bsums + 256;             // [E]
  int* d32    = s32 + E;                 // [E]
  int* flag   = d32 + E;                 // [1]
  float* alpha3 = (float*)s32;           // [E] — s32 dead after scatter_edges

  hipMemsetAsync(deg, 0, N * sizeof(int), stream);
  detect_i64<<<1, 64, 0, stream>>>(edges, flag);
  int eb = (int)((E + 255) / 256);
  norm_edges<<<eb, 256, 0, stream>>>(edges, flag, s32, d32);
  count_deg<<<eb, 256, 0, stream>>>(d32, deg);
  int nb = (int)((N + 255) / 256);
  scan_bsum<<<nb, 256, 0, stream>>>(deg, bsums);
  scan_offsets<<<1, 256, 0, stream>>>(bsums, rowp, nb);
  scan_final<<<nb, 256, 0, stream>>>(deg, bsums, rowp, cursor);
  scatter_edges<<<eb, 256, 0, stream>>>(s32, d32, cursor, srcs);

  dim3 gg((unsigned)((N + 127) / 128), 2);  // 391 x 2
  dim3 g3((unsigned)((N + 127) / 128), 1);

  // layer 1
  cast_x<<<(unsigned)(N * 256 / 4 / 256), 256, 0, stream>>>(x, hb);
  tr_w<<<256, 256, 0, stream>>>(W1, WT);
  gemm_mfma<128><<<gg, 256, 0, stream>>>(hb, WT, h, 256);
  elr_heads<<<(unsigned)N, 256, 0, stream>>>(h, al1, ar1, el, er, hb);
  alpha_heads<<<(unsigned)N, 64, 0, stream>>>(el, er, rowp, srcs, alpha);
  agg_gather<<<(unsigned)N, 256, 0, stream>>>(hb, alpha, b1, rowp, srcs, ob);
  // layer 2
  tr_w<<<256, 256, 0, stream>>>(W2, WT);
  gemm_mfma<128><<<gg, 256, 0, stream>>>(ob, WT, h, 256);
  elr_heads<<<(unsigned)N, 256, 0, stream>>>(h, al2, ar2, el, er, hb);
  alpha_heads<<<(unsigned)N, 64, 0, stream>>>(el, er, rowp, srcs, alpha);
  agg_gather<<<(unsigned)N, 256, 0, stream>>>(hb, alpha, b2, rowp, srcs, ob);
  // layer 3 + fused log_softmax
  tr_w3<<<64, 256, 0, stream>>>(W3, WT3);
  gemm_mfma<64><<<g3, 256, 0, stream>>>(ob, WT3, h3, 64);
  elr_cls<<<(unsigned)N, 64, 0, stream>>>(h3, al3, ar3, el, er);
  alpha_cls<<<(unsigned)N, 64, 0, stream>>>(el, er, rowp, srcs, alpha3);
  agg_cls<<<(unsigned)N, 64, 0, stream>>>(h3, alpha3, b3, rowp, srcs, out);
}

// Round 5
// 500.062 us; speedup vs baseline: 1.8490x; 1.3419x over previous
//
#include <hip/hip_runtime.h>
#include <hip/hip_bf16.h>
#include <math.h>

#define N_NODES 50000
#define N_EDGES 800000
#define NCLASS 40

using f32x4 = __attribute__((ext_vector_type(4))) float;
using s16x8 = __attribute__((ext_vector_type(8))) short;

// ---------------- edge dtype normalize + degree count ----------------
__global__ void detect_i64(const int* __restrict__ raw, int* __restrict__ flag) {
  int t = threadIdx.x;
  int v = raw[2 * t + 1];
  unsigned long long any = __ballot(v != 0);
  if (t == 0) flag[0] = (any == 0ULL) ? 1 : 0;
}

__global__ void norm_count(const int* __restrict__ raw, const int* __restrict__ flag,
                           int* __restrict__ s32, int* __restrict__ d32,
                           int* __restrict__ deg) {
  int e = blockIdx.x * blockDim.x + threadIdx.x;
  if (e >= N_EDGES) return;
  int s, d;
  if (flag[0]) {
    s = raw[2 * e];
    d = raw[2 * N_EDGES + 2 * e];
  } else {
    s = raw[e];
    d = raw[N_EDGES + e];
  }
  s32[e] = s;
  d32[e] = d;
  atomicAdd(&deg[d], 1);
}

// ---------------- CSR build (group edges by dst) ----------------
__global__ void scan_bsum(const int* __restrict__ deg, int* __restrict__ bsums) {
  __shared__ int sm[256];
  int t = threadIdx.x;
  int i = blockIdx.x * 256 + t;
  sm[t] = (i < N_NODES) ? deg[i] : 0;
  __syncthreads();
  for (int off = 128; off > 0; off >>= 1) {
    if (t < off) sm[t] += sm[t + off];
    __syncthreads();
  }
  if (t == 0) bsums[blockIdx.x] = sm[0];
}

__global__ void scan_offsets(int* __restrict__ bsums, int* __restrict__ rowp, int nb) {
  __shared__ int sm[256];
  int t = threadIdx.x;
  int v = (t < nb) ? bsums[t] : 0;
  sm[t] = v;
  __syncthreads();
  for (int off = 1; off < 256; off <<= 1) {
    int add = (t >= off) ? sm[t - off] : 0;
    __syncthreads();
    sm[t] += add;
    __syncthreads();
  }
  if (t < nb) bsums[t] = sm[t] - v;
  if (t == 0) rowp[N_NODES] = N_EDGES;
}

__global__ void scan_final(const int* __restrict__ deg, const int* __restrict__ bsums,
                           int* __restrict__ rowp, int* __restrict__ cursor) {
  __shared__ int sm[256];
  int t = threadIdx.x;
  int i = blockIdx.x * 256 + t;
  int v = (i < N_NODES) ? deg[i] : 0;
  sm[t] = v;
  __syncthreads();
  for (int off = 1; off < 256; off <<= 1) {
    int add = (t >= off) ? sm[t - off] : 0;
    __syncthreads();
    sm[t] += add;
    __syncthreads();
  }
  int excl = sm[t] - v + bsums[blockIdx.x];
  if (i < N_NODES) { rowp[i] = excl; cursor[i] = excl; }
}

__global__ void scatter_edges(const int* __restrict__ s32, const int* __restrict__ d32,
                              int* __restrict__ cursor, int* __restrict__ srcs) {
  int e = blockIdx.x * blockDim.x + threadIdx.x;
  if (e >= N_EDGES) return;
  int d = d32[e];
  int pos = atomicAdd(&cursor[d], 1);
  srcs[pos] = s32[e];
}

// ---------------- weight prep ----------------
__global__ void tr_w(const float* __restrict__ W, __hip_bfloat16* __restrict__ WT) {
  int id = blockIdx.x * 256 + threadIdx.x;  // 65536
  int n = id >> 8, k = id & 255;
  WT[n * 256 + k] = __float2bfloat16(W[k * 256 + n]);
}

__global__ void tr_w3(const float* __restrict__ W3, __hip_bfloat16* __restrict__ WT3) {
  int id = blockIdx.x * 256 + threadIdx.x;  // 16384
  int n = id >> 8, k = id & 255;
  WT3[n * 256 + k] = (n < NCLASS) ? __float2bfloat16(W3[k * NCLASS + n]) : __float2bfloat16(0.f);
}

__global__ void cast_x(const float* __restrict__ x, __hip_bfloat16* __restrict__ xb) {
  int id = blockIdx.x * 256 + threadIdx.x;  // N*256/4 threads
  float4 v = *reinterpret_cast<const float4*>(x + (size_t)id * 4);
  ushort4 u;
  __hip_bfloat16 b;
  b = __float2bfloat16(v.x); u.x = *(unsigned short*)&b;
  b = __float2bfloat16(v.y); u.y = *(unsigned short*)&b;
  b = __float2bfloat16(v.z); u.z = *(unsigned short*)&b;
  b = __float2bfloat16(v.w); u.w = *(unsigned short*)&b;
  *reinterpret_cast<ushort4*>((unsigned short*)xb + (size_t)id * 4) = u;
}

// ---------------- bf16 MFMA GEMM, layers 1-2, fused el/er + bf16-out epilogue ----------
// A[rows,256] bf16; WT [256][256] bf16 (pre-transposed W). BM=128, BN=128, BK=32.
// 4 waves as 2x2; wave tile 64x64 = exactly one head's 64 cols.
__global__ __launch_bounds__(256) void gemm_gat12(const __hip_bfloat16* __restrict__ A,
                                                  const __hip_bfloat16* __restrict__ WT,
                                                  const float* __restrict__ al,
                                                  const float* __restrict__ ar,
                                                  __hip_bfloat16* __restrict__ hb,
                                                  float* __restrict__ el,
                                                  float* __restrict__ er) {
  constexpr int MREP = 4, NREP = 4;
  __shared__ __align__(16) __hip_bfloat16 As[128][40];
  __shared__ __align__(16) __hip_bfloat16 Bs[128][40];

  int t = threadIdx.x;
  int lane = t & 63, wave = t >> 6;
  int wr = wave >> 1, wc = wave & 1;
  int row0 = blockIdx.x * 128, col0 = blockIdx.y * 128;
  int ln = lane & 15;
  int kc8 = (lane >> 4) * 8;

  f32x4 acc[MREP][NREP];
  const f32x4 fz = {0.f, 0.f, 0.f, 0.f};
#pragma unroll
  for (int m = 0; m < MREP; ++m)
#pragma unroll
    for (int n = 0; n < NREP; ++n) acc[m][n] = fz;

  for (int k0 = 0; k0 < 256; k0 += 32) {
#pragma unroll
    for (int it = 0; it < 2; ++it) {
      int c = t + it * 256;
      int r = c >> 2, kc = (c & 3) * 8;
      int grow = row0 + r;
      f32x4 v = fz;
      if (grow < N_NODES)
        v = *reinterpret_cast<const f32x4*>(A + (size_t)grow * 256 + k0 + kc);
      *reinterpret_cast<f32x4*>(&As[r][kc]) = v;
    }
#pragma unroll
    for (int it = 0; it < 2; ++it) {
      int c = t + it * 256;
      int r = c >> 2, kc = (c & 3) * 8;
      f32x4 v = *reinterpret_cast<const f32x4*>(WT + (size_t)(col0 + r) * 256 + k0 + kc);
      *reinterpret_cast<f32x4*>(&Bs[r][kc]) = v;
    }
    __syncthreads();
    s16x8 af[MREP], bfr[NREP];
#pragma unroll
    for (int m = 0; m < MREP; ++m)
      af[m] = *reinterpret_cast<const s16x8*>(&As[wr * 64 + m * 16 + ln][kc8]);
#pragma unroll
    for (int n = 0; n < NREP; ++n)
      bfr[n] = *reinterpret_cast<const s16x8*>(&Bs[wc * 64 + n * 16 + ln][kc8]);
#pragma unroll
    for (int m = 0; m < MREP; ++m)
#pragma unroll
      for (int n = 0; n < NREP; ++n)
        acc[m][n] = __builtin_amdgcn_mfma_f32_16x16x32_bf16(af[m], bfr[n], acc[m][n], 0, 0, 0);
    __syncthreads();
  }

  // epilogue: wave covers head = by*2 + wc (cols head*64 .. +64)
  int head = blockIdx.y * 2 + wc;
  float alv[NREP], arv[NREP];
#pragma unroll
  for (int n = 0; n < NREP; ++n) {
    int c = head * 64 + n * 16 + ln;
    alv[n] = al[c];
    arv[n] = ar[c];
  }
#pragma unroll
  for (int m = 0; m < MREP; ++m) {
#pragma unroll
    for (int r = 0; r < 4; ++r) {
      int row = row0 + wr * 64 + m * 16 + (lane >> 4) * 4 + r;
      bool ok = row < N_NODES;
      float pl = 0.f, pr = 0.f;
#pragma unroll
      for (int n = 0; n < NREP; ++n) {
        float v = acc[m][n][r];
        pl += v * alv[n];
        pr += v * arv[n];
        if (ok) hb[(size_t)row * 256 + head * 64 + n * 16 + ln] = __float2bfloat16(v);
      }
      for (int off = 1; off < 16; off <<= 1) {
        pl += __shfl_xor(pl, off);
        pr += __shfl_xor(pr, off);
      }
      if (ln == 0 && ok) {
        el[row * 4 + head] = pl;
        er[row * 4 + head] = pr;
      }
    }
  }
}

// ---------------- layer-3 GEMM: BN=64 (cols 0-63, 40 live), fused el/er, fp32 out ------
__global__ __launch_bounds__(256) void gemm_gat3(const __hip_bfloat16* __restrict__ A,
                                                 const __hip_bfloat16* __restrict__ WT,
                                                 const float* __restrict__ al,
                                                 const float* __restrict__ ar,
                                                 float* __restrict__ h3,
                                                 float* __restrict__ el,
                                                 float* __restrict__ er) {
  constexpr int MREP = 2, NREP = 4;
  __shared__ __align__(16) __hip_bfloat16 As[128][40];
  __shared__ __align__(16) __hip_bfloat16 Bs[64][40];

  int t = threadIdx.x;
  int lane = t & 63, wave = t >> 6;
  int row0 = blockIdx.x * 128;
  int ln = lane & 15;
  int kc8 = (lane >> 4) * 8;

  f32x4 acc[MREP][NREP];
  const f32x4 fz = {0.f, 0.f, 0.f, 0.f};
#pragma unroll
  for (int m = 0; m < MREP; ++m)
#pragma unroll
    for (int n = 0; n < NREP; ++n) acc[m][n] = fz;

  for (int k0 = 0; k0 < 256; k0 += 32) {
#pragma unroll
    for (int it = 0; it < 2; ++it) {
      int c = t + it * 256;
      int r = c >> 2, kc = (c & 3) * 8;
      int grow = row0 + r;
      f32x4 v = fz;
      if (grow < N_NODES)
        v = *reinterpret_cast<const f32x4*>(A + (size_t)grow * 256 + k0 + kc);
      *reinterpret_cast<f32x4*>(&As[r][kc]) = v;
    }
    {
      int c = t;
      int r = c >> 2, kc = (c & 3) * 8;
      f32x4 v = *reinterpret_cast<const f32x4*>(WT + (size_t)r * 256 + k0 + kc);
      *reinterpret_cast<f32x4*>(&Bs[r][kc]) = v;
    }
    __syncthreads();
    s16x8 af[MREP], bfr[NREP];
#pragma unroll
    for (int m = 0; m < MREP; ++m)
      af[m] = *reinterpret_cast<const s16x8*>(&As[wave * 32 + m * 16 + ln][kc8]);
#pragma unroll
    for (int n = 0; n < NREP; ++n)
      bfr[n] = *reinterpret_cast<const s16x8*>(&Bs[n * 16 + ln][kc8]);
#pragma unroll
    for (int m = 0; m < MREP; ++m)
#pragma unroll
      for (int n = 0; n < NREP; ++n)
        acc[m][n] = __builtin_amdgcn_mfma_f32_16x16x32_bf16(af[m], bfr[n], acc[m][n], 0, 0, 0);
    __syncthreads();
  }

  float alv[NREP], arv[NREP];
#pragma unroll
  for (int n = 0; n < NREP; ++n) {
    int c = n * 16 + ln;
    alv[n] = (c < NCLASS) ? al[c] : 0.f;
    arv[n] = (c < NCLASS) ? ar[c] : 0.f;
  }
#pragma unroll
  for (int m = 0; m < MREP; ++m) {
#pragma unroll
    for (int r = 0; r < 4; ++r) {
      int row = row0 + wave * 32 + m * 16 + (lane >> 4) * 4 + r;
      bool ok = row < N_NODES;
      float pl = 0.f, pr = 0.f;
#pragma unroll
      for (int n = 0; n < NREP; ++n) {
        float v = acc[m][n][r];
        pl += v * alv[n];
        pr += v * arv[n];
        if (ok) h3[(size_t)row * 64 + n * 16 + ln] = v;
      }
      for (int off = 1; off < 16; off <<= 1) {
        pl += __shfl_xor(pl, off);
        pr += __shfl_xor(pr, off);
      }
      if (ln == 0 && ok) {
        el[row] = pl;
        er[row] = pr;
      }
    }
  }
}

// ---------------- normalized edge weights (4 heads): 2-pass, e cached in alpha -------
__global__ __launch_bounds__(64) void alpha_heads(const float* __restrict__ el,
                                                  const float* __restrict__ er,
                                                  const int* __restrict__ rowp,
                                                  const int* __restrict__ srcs,
                                                  float* __restrict__ alpha) {
  int n = blockIdx.x;
  int lane = threadIdx.x;
  int head = lane & 3, slot = lane >> 2;
  int i0 = rowp[n], i1 = rowp[n + 1];
  float ern = er[n * 4 + head];
  float m = -1e30f, l = 0.f;
  for (int base = i0; base < i1; base += 16) {
    int i = base + slot;
    float e = -1e30f;
    if (i < i1) {
      int s = srcs[i];
      e = el[s * 4 + head] + ern;
      e = (e >= 0.f) ? e : 0.2f * e;
      alpha[(size_t)i * 4 + head] = e;  // cache raw score
    }
    float nm = fmaxf(m, e);
    l = l * __expf(m - nm) + ((i < i1) ? __expf(e - nm) : 0.f);
    m = nm;
  }
  for (int off = 4; off <= 32; off <<= 1) {
    float mo = __shfl_xor(m, off);
    float lo = __shfl_xor(l, off);
    float nm = fmaxf(m, mo);
    l = l * __expf(m - nm) + lo * __expf(mo - nm);
    m = nm;
  }
  float inv = (l > 0.f) ? (1.f / l) : 0.f;
  for (int base = i0; base < i1; base += 16) {
    int i = base + slot;
    if (i < i1) {
      float e = alpha[(size_t)i * 4 + head];  // contiguous re-read
      alpha[(size_t)i * 4 + head] = __expf(e - m) * inv;
    }
  }
}

__global__ __launch_bounds__(64) void alpha_cls(const float* __restrict__ el,
                                                const float* __restrict__ er,
                                                const int* __restrict__ rowp,
                                                const int* __restrict__ srcs,
                                                float* __restrict__ alpha) {
  int n = blockIdx.x;
  int slot = threadIdx.x;
  int i0 = rowp[n], i1 = rowp[n + 1];
  float ern = er[n];
  float m = -1e30f, l = 0.f;
  for (int base = i0; base < i1; base += 64) {
    int i = base + slot;
    float e = -1e30f;
    if (i < i1) {
      int s = srcs[i];
      e = el[s] + ern;
      e = (e >= 0.f) ? e : 0.2f * e;
      alpha[i] = e;
    }
    float nm = fmaxf(m, e);
    l = l * __expf(m - nm) + ((i < i1) ? __expf(e - nm) : 0.f);
    m = nm;
  }
  for (int off = 1; off <= 32; off <<= 1) {
    float mo = __shfl_xor(m, off);
    float lo = __shfl_xor(l, off);
    float nm = fmaxf(m, mo);
    l = l * __expf(m - nm) + lo * __expf(mo - nm);
    m = nm;
  }
  float inv = (l > 0.f) ? (1.f / l) : 0.f;
  for (int base = i0; base < i1; base += 64) {
    int i = base + slot;
    if (i < i1) alpha[i] = __expf(alpha[i] - m) * inv;
  }
}

// ---------------- weighted gather (+bias+ELU), 128 threads, dword loads -------------
__global__ __launch_bounds__(128) void agg_gather(const __hip_bfloat16* __restrict__ hb,
                                                  const float* __restrict__ alpha,
                                                  const float* __restrict__ bias,
                                                  const int* __restrict__ rowp,
                                                  const int* __restrict__ srcs,
                                                  __hip_bfloat16* __restrict__ ob) {
  int n = blockIdx.x, t = threadIdx.x;  // t handles dims {2t, 2t+1}
  int head = t >> 5;                    // (2t)>>6
  const unsigned int* hp = (const unsigned int*)hb;
  int i0 = rowp[n], i1 = rowp[n + 1];
  float ax0 = 0.f, ax1 = 0.f, ax2 = 0.f, ax3 = 0.f;
  float ay0 = 0.f, ay1 = 0.f, ay2 = 0.f, ay3 = 0.f;
  int i = i0;
  for (; i + 3 < i1; i += 4) {
    int s0 = srcs[i], s1 = srcs[i + 1], s2 = srcs[i + 2], s3 = srcs[i + 3];
    float a0 = alpha[(size_t)i * 4 + head];
    float a1 = alpha[(size_t)(i + 1) * 4 + head];
    float a2 = alpha[(size_t)(i + 2) * 4 + head];
    float a3 = alpha[(size_t)(i + 3) * 4 + head];
    unsigned int w0 = hp[(size_t)s0 * 128 + t];
    unsigned int w1 = hp[(size_t)s1 * 128 + t];
    unsigned int w2 = hp[(size_t)s2 * 128 + t];
    unsigned int w3 = hp[(size_t)s3 * 128 + t];
    ax0 += a0 * __uint_as_float(w0 << 16);
    ay0 += a0 * __uint_as_float(w0 & 0xffff0000u);
    ax1 += a1 * __uint_as_float(w1 << 16);
    ay1 += a1 * __uint_as_float(w1 & 0xffff0000u);
    ax2 += a2 * __uint_as_float(w2 << 16);
    ay2 += a2 * __uint_as_float(w2 & 0xffff0000u);
    ax3 += a3 * __uint_as_float(w3 << 16);
    ay3 += a3 * __uint_as_float(w3 & 0xffff0000u);
  }
  for (; i < i1; ++i) {
    int s0 = srcs[i];
    float a0 = alpha[(size_t)i * 4 + head];
    unsigned int w0 = hp[(size_t)s0 * 128 + t];
    ax0 += a0 * __uint_as_float(w0 << 16);
    ay0 += a0 * __uint_as_float(w0 & 0xffff0000u);
  }
  float v0 = ax0 + ax1 + ax2 + ax3 + bias[2 * t];
  float v1 = ay0 + ay1 + ay2 + ay3 + bias[2 * t + 1];
  v0 = (v0 > 0.f) ? v0 : (__expf(v0) - 1.f);
  v1 = (v1 > 0.f) ? v1 : (__expf(v1) - 1.f);
  __hip_bfloat16 b0 = __float2bfloat16(v0), b1 = __float2bfloat16(v1);
  unsigned int packed = (unsigned int)(*(unsigned short*)&b0) |
                        ((unsigned int)(*(unsigned short*)&b1) << 16);
  ((unsigned int*)ob)[(size_t)n * 128 + t] = packed;
}

// layer 3 gather + bias + fused log_softmax (h3 fp32 [N,64], 1 head)
__global__ __launch_bounds__(64) void agg_cls(const float* __restrict__ h3,
                                              const float* __restrict__ alpha,
                                              const float* __restrict__ bias,
                                              const int* __restrict__ rowp,
                                              const int* __restrict__ srcs,
                                              float* __restrict__ out) {
  int n = blockIdx.x, t = threadIdx.x;
  bool act = t < NCLASS;
  int i0 = rowp[n], i1 = rowp[n + 1];
  float acc0 = 0.f, acc1 = 0.f;
  int i = i0;
  for (; i + 1 < i1; i += 2) {
    int s0 = srcs[i], s1 = srcs[i + 1];
    float a0 = alpha[i], a1 = alpha[i + 1];
    if (act) {
      acc0 += a0 * h3[(size_t)s0 * 64 + t];
      acc1 += a1 * h3[(size_t)s1 * 64 + t];
    }
  }
  if (i < i1 && act) acc0 += alpha[i] * h3[(size_t)srcs[i] * 64 + t];
  float z = acc0 + acc1 + (act ? bias[t] : 0.f);
  float zz = act ? z : -INFINITY;
  float mx = zz;
  for (int off = 32; off > 0; off >>= 1) mx = fmaxf(mx, __shfl_xor(mx, off));
  float ex = act ? __expf(z - mx) : 0.f;
  float sum = ex;
  for (int off = 32; off > 0; off >>= 1) sum += __shfl_xor(sum, off);
  if (act) out[(size_t)n * NCLASS + t] = z - mx - __logf(sum);
}

extern "C" void kernel_launch(void* const* d_in, const int* in_sizes, int n_in,
                              void* d_out, int out_size, void* d_ws, size_t ws_size,
                              hipStream_t stream) {
  const float* x   = (const float*)d_in[0];
  const int* edges = (const int*)d_in[1];
  const float* W1  = (const float*)d_in[2];
  const float* al1 = (const float*)d_in[3];
  const float* ar1 = (const float*)d_in[4];
  const float* b1  = (const float*)d_in[5];
  const float* W2  = (const float*)d_in[6];
  const float* al2 = (const float*)d_in[7];
  const float* ar2 = (const float*)d_in[8];
  const float* b2  = (const float*)d_in[9];
  const float* W3  = (const float*)d_in[10];
  const float* al3 = (const float*)d_in[11];
  const float* ar3 = (const float*)d_in[12];
  const float* b3  = (const float*)d_in[13];
  float* out = (float*)d_out;

  const size_t N = N_NODES, E = N_EDGES;
  float* h3 = (float*)d_ws;              // [N,64] fp32
  float* el = h3 + N * 64;               // [N,4]
  float* er = el + N * 4;                // [N,4]
  float* alpha = er + N * 4;             // [E,4]
  __hip_bfloat16* xb = (__hip_bfloat16*)(alpha + E * 4);  // [N,256]
  __hip_bfloat16* hb = xb + N * 256;     // [N,256]
  __hip_bfloat16* ob = hb + N * 256;     // [N,256]
  __hip_bfloat16* WT = ob + N * 256;     // [256,256]
  __hip_bfloat16* WT3 = WT + 256 * 256;  // [64,256]
  int* rowp   = (int*)(WT3 + 64 * 256);  // [N+1]
  int* cursor = rowp + (N + 1);          // [N]
  int* srcs   = cursor + N;              // [E]
  int* deg    = srcs + E;                // [N]
  int* bsums  = deg + N;                 // [256]
  int* s32    = bsums + 256;             // [E]
  int* d32    = s32 + E;                 // [E]
  int* flag   = d32 + E;                 // [1]
  float* alpha3 = (float*)s32;           // [E] — s32 dead after scatter_edges

  hipMemsetAsync(deg, 0, N * sizeof(int), stream);
  detect_i64<<<1, 64, 0, stream>>>(edges, flag);
  int eb = (int)((E + 255) / 256);
  norm_count<<<eb, 256, 0, stream>>>(edges, flag, s32, d32, deg);
  int nb = (int)((N + 255) / 256);
  scan_bsum<<<nb, 256, 0, stream>>>(deg, bsums);
  scan_offsets<<<1, 256, 0, stream>>>(bsums, rowp, nb);
  scan_final<<<nb, 256, 0, stream>>>(deg, bsums, rowp, cursor);
  scatter_edges<<<eb, 256, 0, stream>>>(s32, d32, cursor, srcs);

  dim3 gg((unsigned)((N + 127) / 128), 2);  // 391 x 2
  dim3 g3((unsigned)((N + 127) / 128), 1);

  // layer 1
  cast_x<<<(unsigned)(N * 256 / 4 / 256), 256, 0, stream>>>(x, xb);
  tr_w<<<256, 256, 0, stream>>>(W1, WT);
  gemm_gat12<<<gg, 256, 0, stream>>>(xb, WT, al1, ar1, hb, el, er);
  alpha_heads<<<(unsigned)N, 64, 0, stream>>>(el, er, rowp, srcs, alpha);
  agg_gather<<<(unsigned)N, 128, 0, stream>>>(hb, alpha, b1, rowp, srcs, ob);
  // layer 2
  tr_w<<<256, 256, 0, stream>>>(W2, WT);
  gemm_gat12<<<gg, 256, 0, stream>>>(ob, WT, al2, ar2, hb, el, er);
  alpha_heads<<<(unsigned)N, 64, 0, stream>>>(el, er, rowp, srcs, alpha);
  agg_gather<<<(unsigned)N, 128, 0, stream>>>(hb, alpha, b2, rowp, srcs, ob);
  // layer 3 + fused log_softmax
  tr_w3<<<64, 256, 0, stream>>>(W3, WT3);
  gemm_gat3<<<g3, 256, 0, stream>>>(ob, WT3, al3, ar3, h3, el, er);
  alpha_cls<<<(unsigned)N, 64, 0, stream>>>(el, er, rowp, srcs, alpha3);
  agg_cls<<<(unsigned)N, 64, 0, stream>>>(h3, alpha3, b3, rowp, srcs, out);
}

// Round 6
// 474.350 us; speedup vs baseline: 1.9492x; 1.0542x over previous
//
#include <hip/hip_runtime.h>
#include <hip/hip_bf16.h>
#include <math.h>

#define N_NODES 50000
#define N_EDGES 800000
#define NCLASS 40
#define MAXE 512

using f32x4 = __attribute__((ext_vector_type(4))) float;
using s16x8 = __attribute__((ext_vector_type(8))) short;

// ---------------- edge dtype normalize + degree count ----------------
__global__ void detect_i64(const int* __restrict__ raw, int* __restrict__ flag) {
  int t = threadIdx.x;
  int v = raw[2 * t + 1];
  unsigned long long any = __ballot(v != 0);
  if (t == 0) flag[0] = (any == 0ULL) ? 1 : 0;
}

__global__ void norm_count(const int* __restrict__ raw, const int* __restrict__ flag,
                           int* __restrict__ s32, int* __restrict__ d32,
                           int* __restrict__ deg) {
  int e = blockIdx.x * blockDim.x + threadIdx.x;
  if (e >= N_EDGES) return;
  int s, d;
  if (flag[0]) {
    s = raw[2 * e];
    d = raw[2 * N_EDGES + 2 * e];
  } else {
    s = raw[e];
    d = raw[N_EDGES + e];
  }
  s32[e] = s;
  d32[e] = d;
  atomicAdd(&deg[d], 1);
}

// ---------------- CSR build (group edges by dst) ----------------
__global__ void scan_bsum(const int* __restrict__ deg, int* __restrict__ bsums) {
  __shared__ int sm[256];
  int t = threadIdx.x;
  int i = blockIdx.x * 256 + t;
  sm[t] = (i < N_NODES) ? deg[i] : 0;
  __syncthreads();
  for (int off = 128; off > 0; off >>= 1) {
    if (t < off) sm[t] += sm[t + off];
    __syncthreads();
  }
  if (t == 0) bsums[blockIdx.x] = sm[0];
}

__global__ void scan_offsets(int* __restrict__ bsums, int* __restrict__ rowp, int nb) {
  __shared__ int sm[256];
  int t = threadIdx.x;
  int v = (t < nb) ? bsums[t] : 0;
  sm[t] = v;
  __syncthreads();
  for (int off = 1; off < 256; off <<= 1) {
    int add = (t >= off) ? sm[t - off] : 0;
    __syncthreads();
    sm[t] += add;
    __syncthreads();
  }
  if (t < nb) bsums[t] = sm[t] - v;
  if (t == 0) rowp[N_NODES] = N_EDGES;
}

__global__ void scan_final(const int* __restrict__ deg, const int* __restrict__ bsums,
                           int* __restrict__ rowp, int* __restrict__ cursor) {
  __shared__ int sm[256];
  int t = threadIdx.x;
  int i = blockIdx.x * 256 + t;
  int v = (i < N_NODES) ? deg[i] : 0;
  sm[t] = v;
  __syncthreads();
  for (int off = 1; off < 256; off <<= 1) {
    int add = (t >= off) ? sm[t - off] : 0;
    __syncthreads();
    sm[t] += add;
    __syncthreads();
  }
  int excl = sm[t] - v + bsums[blockIdx.x];
  if (i < N_NODES) { rowp[i] = excl; cursor[i] = excl; }
}

__global__ void scatter_edges(const int* __restrict__ s32, const int* __restrict__ d32,
                              int* __restrict__ cursor, int* __restrict__ srcs) {
  int e = blockIdx.x * blockDim.x + threadIdx.x;
  if (e >= N_EDGES) return;
  int d = d32[e];
  int pos = atomicAdd(&cursor[d], 1);
  srcs[pos] = s32[e];
}

// ---------------- weight prep ----------------
__global__ void tr_w(const float* __restrict__ W, __hip_bfloat16* __restrict__ WT) {
  int id = blockIdx.x * 256 + threadIdx.x;  // 65536
  int n = id >> 8, k = id & 255;
  WT[n * 256 + k] = __float2bfloat16(W[k * 256 + n]);
}

__global__ void tr_w3(const float* __restrict__ W3, __hip_bfloat16* __restrict__ WT3) {
  int id = blockIdx.x * 256 + threadIdx.x;  // 16384
  int n = id >> 8, k = id & 255;
  WT3[n * 256 + k] = (n < NCLASS) ? __float2bfloat16(W3[k * NCLASS + n]) : __float2bfloat16(0.f);
}

__global__ void cast_x(const float* __restrict__ x, __hip_bfloat16* __restrict__ xb) {
  int id = blockIdx.x * 256 + threadIdx.x;  // N*256/4 threads
  float4 v = *reinterpret_cast<const float4*>(x + (size_t)id * 4);
  ushort4 u;
  __hip_bfloat16 b;
  b = __float2bfloat16(v.x); u.x = *(unsigned short*)&b;
  b = __float2bfloat16(v.y); u.y = *(unsigned short*)&b;
  b = __float2bfloat16(v.z); u.z = *(unsigned short*)&b;
  b = __float2bfloat16(v.w); u.w = *(unsigned short*)&b;
  *reinterpret_cast<ushort4*>((unsigned short*)xb + (size_t)id * 4) = u;
}

// ---------------- bf16 MFMA GEMM, layers 1-2, fused el/er + bf16-out epilogue ----------
__global__ __launch_bounds__(256) void gemm_gat12(const __hip_bfloat16* __restrict__ A,
                                                  const __hip_bfloat16* __restrict__ WT,
                                                  const float* __restrict__ al,
                                                  const float* __restrict__ ar,
                                                  __hip_bfloat16* __restrict__ hb,
                                                  float* __restrict__ el,
                                                  float* __restrict__ er) {
  constexpr int MREP = 4, NREP = 4;
  __shared__ __align__(16) __hip_bfloat16 As[128][40];
  __shared__ __align__(16) __hip_bfloat16 Bs[128][40];

  int t = threadIdx.x;
  int lane = t & 63, wave = t >> 6;
  int wr = wave >> 1, wc = wave & 1;
  int row0 = blockIdx.x * 128, col0 = blockIdx.y * 128;
  int ln = lane & 15;
  int kc8 = (lane >> 4) * 8;

  f32x4 acc[MREP][NREP];
  const f32x4 fz = {0.f, 0.f, 0.f, 0.f};
#pragma unroll
  for (int m = 0; m < MREP; ++m)
#pragma unroll
    for (int n = 0; n < NREP; ++n) acc[m][n] = fz;

  for (int k0 = 0; k0 < 256; k0 += 32) {
#pragma unroll
    for (int it = 0; it < 2; ++it) {
      int c = t + it * 256;
      int r = c >> 2, kc = (c & 3) * 8;
      int grow = row0 + r;
      f32x4 v = fz;
      if (grow < N_NODES)
        v = *reinterpret_cast<const f32x4*>(A + (size_t)grow * 256 + k0 + kc);
      *reinterpret_cast<f32x4*>(&As[r][kc]) = v;
    }
#pragma unroll
    for (int it = 0; it < 2; ++it) {
      int c = t + it * 256;
      int r = c >> 2, kc = (c & 3) * 8;
      f32x4 v = *reinterpret_cast<const f32x4*>(WT + (size_t)(col0 + r) * 256 + k0 + kc);
      *reinterpret_cast<f32x4*>(&Bs[r][kc]) = v;
    }
    __syncthreads();
    s16x8 af[MREP], bfr[NREP];
#pragma unroll
    for (int m = 0; m < MREP; ++m)
      af[m] = *reinterpret_cast<const s16x8*>(&As[wr * 64 + m * 16 + ln][kc8]);
#pragma unroll
    for (int n = 0; n < NREP; ++n)
      bfr[n] = *reinterpret_cast<const s16x8*>(&Bs[wc * 64 + n * 16 + ln][kc8]);
#pragma unroll
    for (int m = 0; m < MREP; ++m)
#pragma unroll
      for (int n = 0; n < NREP; ++n)
        acc[m][n] = __builtin_amdgcn_mfma_f32_16x16x32_bf16(af[m], bfr[n], acc[m][n], 0, 0, 0);
    __syncthreads();
  }

  int head = blockIdx.y * 2 + wc;
  float alv[NREP], arv[NREP];
#pragma unroll
  for (int n = 0; n < NREP; ++n) {
    int c = head * 64 + n * 16 + ln;
    alv[n] = al[c];
    arv[n] = ar[c];
  }
#pragma unroll
  for (int m = 0; m < MREP; ++m) {
#pragma unroll
    for (int r = 0; r < 4; ++r) {
      int row = row0 + wr * 64 + m * 16 + (lane >> 4) * 4 + r;
      bool ok = row < N_NODES;
      float pl = 0.f, pr = 0.f;
#pragma unroll
      for (int n = 0; n < NREP; ++n) {
        float v = acc[m][n][r];
        pl += v * alv[n];
        pr += v * arv[n];
        if (ok) hb[(size_t)row * 256 + head * 64 + n * 16 + ln] = __float2bfloat16(v);
      }
      for (int off = 1; off < 16; off <<= 1) {
        pl += __shfl_xor(pl, off);
        pr += __shfl_xor(pr, off);
      }
      if (ln == 0 && ok) {
        el[row * 4 + head] = pl;
        er[row * 4 + head] = pr;
      }
    }
  }
}

// ---------------- layer-3 GEMM: fused el/er, bf16 h3 out ----------------
__global__ __launch_bounds__(256) void gemm_gat3(const __hip_bfloat16* __restrict__ A,
                                                 const __hip_bfloat16* __restrict__ WT,
                                                 const float* __restrict__ al,
                                                 const float* __restrict__ ar,
                                                 __hip_bfloat16* __restrict__ h3b,
                                                 float* __restrict__ el3,
                                                 float* __restrict__ er3) {
  constexpr int MREP = 2, NREP = 4;
  __shared__ __align__(16) __hip_bfloat16 As[128][40];
  __shared__ __align__(16) __hip_bfloat16 Bs[64][40];

  int t = threadIdx.x;
  int lane = t & 63, wave = t >> 6;
  int row0 = blockIdx.x * 128;
  int ln = lane & 15;
  int kc8 = (lane >> 4) * 8;

  f32x4 acc[MREP][NREP];
  const f32x4 fz = {0.f, 0.f, 0.f, 0.f};
#pragma unroll
  for (int m = 0; m < MREP; ++m)
#pragma unroll
    for (int n = 0; n < NREP; ++n) acc[m][n] = fz;

  for (int k0 = 0; k0 < 256; k0 += 32) {
#pragma unroll
    for (int it = 0; it < 2; ++it) {
      int c = t + it * 256;
      int r = c >> 2, kc = (c & 3) * 8;
      int grow = row0 + r;
      f32x4 v = fz;
      if (grow < N_NODES)
        v = *reinterpret_cast<const f32x4*>(A + (size_t)grow * 256 + k0 + kc);
      *reinterpret_cast<f32x4*>(&As[r][kc]) = v;
    }
    {
      int c = t;
      int r = c >> 2, kc = (c & 3) * 8;
      f32x4 v = *reinterpret_cast<const f32x4*>(WT + (size_t)r * 256 + k0 + kc);
      *reinterpret_cast<f32x4*>(&Bs[r][kc]) = v;
    }
    __syncthreads();
    s16x8 af[MREP], bfr[NREP];
#pragma unroll
    for (int m = 0; m < MREP; ++m)
      af[m] = *reinterpret_cast<const s16x8*>(&As[wave * 32 + m * 16 + ln][kc8]);
#pragma unroll
    for (int n = 0; n < NREP; ++n)
      bfr[n] = *reinterpret_cast<const s16x8*>(&Bs[n * 16 + ln][kc8]);
#pragma unroll
    for (int m = 0; m < MREP; ++m)
#pragma unroll
      for (int n = 0; n < NREP; ++n)
        acc[m][n] = __builtin_amdgcn_mfma_f32_16x16x32_bf16(af[m], bfr[n], acc[m][n], 0, 0, 0);
    __syncthreads();
  }

  float alv[NREP], arv[NREP];
#pragma unroll
  for (int n = 0; n < NREP; ++n) {
    int c = n * 16 + ln;
    alv[n] = (c < NCLASS) ? al[c] : 0.f;
    arv[n] = (c < NCLASS) ? ar[c] : 0.f;
  }
#pragma unroll
  for (int m = 0; m < MREP; ++m) {
#pragma unroll
    for (int r = 0; r < 4; ++r) {
      int row = row0 + wave * 32 + m * 16 + (lane >> 4) * 4 + r;
      bool ok = row < N_NODES;
      float pl = 0.f, pr = 0.f;
#pragma unroll
      for (int n = 0; n < NREP; ++n) {
        float v = acc[m][n][r];
        pl += v * alv[n];
        pr += v * arv[n];
        if (ok) h3b[(size_t)row * 64 + n * 16 + ln] = __float2bfloat16(v);
      }
      for (int off = 1; off < 16; off <<= 1) {
        pl += __shfl_xor(pl, off);
        pr += __shfl_xor(pr, off);
      }
      if (ln == 0 && ok) {
        el3[row] = pl;
        er3[row] = pr;
      }
    }
  }
}

// ---------------- fused softmax-stats + weighted gather (+bias+ELU), layers 1-2 ------
// 128 threads: head = t>>5 (4 groups of 32). Pass A: stats from el; scores cached in LDS.
// Cooperative convert scores->weights; Pass B: dword gather with LDS-broadcast weights.
__global__ __launch_bounds__(128) void agg_fused(const __hip_bfloat16* __restrict__ hb,
                                                 const float* __restrict__ el,
                                                 const float* __restrict__ er,
                                                 const float* __restrict__ bias,
                                                 const int* __restrict__ rowp,
                                                 const int* __restrict__ srcs,
                                                 __hip_bfloat16* __restrict__ ob) {
  __shared__ float eld[MAXE * 5];  // [j*5 + head], stride-5 to dodge bank conflicts
  __shared__ float mi[8];
  int n = blockIdx.x, t = threadIdx.x;
  int head = t >> 5, slot = t & 31;
  int i0 = rowp[n], deg = rowp[n + 1] - i0;
  float ern = er[n * 4 + head];
  // pass A: per-thread online max/sum over strided edges
  float m = -1e30f, l = 0.f;
  for (int j = slot; j < deg; j += 32) {
    int s = srcs[i0 + j];
    float e = el[s * 4 + head] + ern;
    e = (e >= 0.f) ? e : 0.2f * e;
    if (j < MAXE) eld[j * 5 + head] = e;
    float nm = fmaxf(m, e);
    l = l * __expf(m - nm) + __expf(e - nm);
    m = nm;
  }
  // butterfly over the 32-lane head group
  for (int off = 1; off < 32; off <<= 1) {
    float mo = __shfl_xor(m, off), lo = __shfl_xor(l, off);
    float nm = fmaxf(m, mo);
    l = l * __expf(m - nm) + lo * __expf(mo - nm);
    m = nm;
  }
  float inv = (l > 0.f) ? (1.f / l) : 0.f;
  if (slot == 0) { mi[head] = m; mi[4 + head] = inv; }
  __syncthreads();
  // convert cached scores -> normalized weights
  int ecount = (deg < MAXE) ? deg : MAXE;
  for (int k = t; k < ecount * 4; k += 128) {
    int j = k >> 2, hh = k & 3;
    eld[j * 5 + hh] = __expf(eld[j * 5 + hh] - mi[hh]) * mi[4 + hh];
  }
  __syncthreads();
  // pass B: dword gather, t handles dims {2t, 2t+1}
  const unsigned int* hp = (const unsigned int*)hb;
  float ax0 = 0.f, ax1 = 0.f, ax2 = 0.f, ax3 = 0.f;
  float ay0 = 0.f, ay1 = 0.f, ay2 = 0.f, ay3 = 0.f;
  int j = 0;
  for (; j + 3 < deg; j += 4) {
    int s0 = srcs[i0 + j], s1 = srcs[i0 + j + 1], s2 = srcs[i0 + j + 2], s3 = srcs[i0 + j + 3];
    float w0, w1, w2, w3;
    if (j + 3 < MAXE) {
      w0 = eld[(j + 0) * 5 + head];
      w1 = eld[(j + 1) * 5 + head];
      w2 = eld[(j + 2) * 5 + head];
      w3 = eld[(j + 3) * 5 + head];
    } else {
      float e0 = el[s0 * 4 + head] + ern; e0 = (e0 >= 0.f) ? e0 : 0.2f * e0;
      float e1 = el[s1 * 4 + head] + ern; e1 = (e1 >= 0.f) ? e1 : 0.2f * e1;
      float e2 = el[s2 * 4 + head] + ern; e2 = (e2 >= 0.f) ? e2 : 0.2f * e2;
      float e3 = el[s3 * 4 + head] + ern; e3 = (e3 >= 0.f) ? e3 : 0.2f * e3;
      w0 = __expf(e0 - m) * inv;
      w1 = __expf(e1 - m) * inv;
      w2 = __expf(e2 - m) * inv;
      w3 = __expf(e3 - m) * inv;
    }
    unsigned int h0 = hp[(size_t)s0 * 128 + t];
    unsigned int h1 = hp[(size_t)s1 * 128 + t];
    unsigned int h2 = hp[(size_t)s2 * 128 + t];
    unsigned int h3v = hp[(size_t)s3 * 128 + t];
    ax0 += w0 * __uint_as_float(h0 << 16);
    ay0 += w0 * __uint_as_float(h0 & 0xffff0000u);
    ax1 += w1 * __uint_as_float(h1 << 16);
    ay1 += w1 * __uint_as_float(h1 & 0xffff0000u);
    ax2 += w2 * __uint_as_float(h2 << 16);
    ay2 += w2 * __uint_as_float(h2 & 0xffff0000u);
    ax3 += w3 * __uint_as_float(h3v << 16);
    ay3 += w3 * __uint_as_float(h3v & 0xffff0000u);
  }
  for (; j < deg; ++j) {
    int s0 = srcs[i0 + j];
    float w0;
    if (j < MAXE) {
      w0 = eld[j * 5 + head];
    } else {
      float e0 = el[s0 * 4 + head] + ern; e0 = (e0 >= 0.f) ? e0 : 0.2f * e0;
      w0 = __expf(e0 - m) * inv;
    }
    unsigned int h0 = hp[(size_t)s0 * 128 + t];
    ax0 += w0 * __uint_as_float(h0 << 16);
    ay0 += w0 * __uint_as_float(h0 & 0xffff0000u);
  }
  float v0 = (ax0 + ax1) + (ax2 + ax3) + bias[2 * t];
  float v1 = (ay0 + ay1) + (ay2 + ay3) + bias[2 * t + 1];
  v0 = (v0 > 0.f) ? v0 : (__expf(v0) - 1.f);
  v1 = (v1 > 0.f) ? v1 : (__expf(v1) - 1.f);
  __hip_bfloat16 b0 = __float2bfloat16(v0), b1 = __float2bfloat16(v1);
  unsigned int packed = (unsigned int)(*(unsigned short*)&b0) |
                        ((unsigned int)(*(unsigned short*)&b1) << 16);
  ((unsigned int*)ob)[(size_t)n * 128 + t] = packed;
}

// ---------------- layer 3: fused stats + gather + bias + log_softmax ----------------
__global__ __launch_bounds__(64) void agg_cls_fused(const __hip_bfloat16* __restrict__ h3b,
                                                    const float* __restrict__ el3,
                                                    const float* __restrict__ er3,
                                                    const float* __restrict__ bias,
                                                    const int* __restrict__ rowp,
                                                    const int* __restrict__ srcs,
                                                    float* __restrict__ out) {
  __shared__ float eldc[MAXE];
  int n = blockIdx.x, t = threadIdx.x;
  int i0 = rowp[n], deg = rowp[n + 1] - i0;
  float ern = er3[n];
  float m = -1e30f, l = 0.f;
  for (int j = t; j < deg; j += 64) {
    int s = srcs[i0 + j];
    float e = el3[s] + ern;
    e = (e >= 0.f) ? e : 0.2f * e;
    if (j < MAXE) eldc[j] = e;
    float nm = fmaxf(m, e);
    l = l * __expf(m - nm) + __expf(e - nm);
    m = nm;
  }
  for (int off = 1; off < 64; off <<= 1) {
    float mo = __shfl_xor(m, off), lo = __shfl_xor(l, off);
    float nm = fmaxf(m, mo);
    l = l * __expf(m - nm) + lo * __expf(mo - nm);
    m = nm;
  }
  float inv = (l > 0.f) ? (1.f / l) : 0.f;
  __syncthreads();
  int ecount = (deg < MAXE) ? deg : MAXE;
  for (int k = t; k < ecount; k += 64) eldc[k] = __expf(eldc[k] - m) * inv;
  __syncthreads();
  bool act2 = t < ((NCLASS + 1) / 2);  // t < 20, dims {2t, 2t+1}
  const unsigned int* hp3 = (const unsigned int*)h3b;
  float ax = 0.f, ay = 0.f, bx = 0.f, by = 0.f;
  int j = 0;
  for (; j + 1 < deg; j += 2) {
    int s0 = srcs[i0 + j], s1 = srcs[i0 + j + 1];
    float w0, w1;
    if (j + 1 < MAXE) {
      w0 = eldc[j];
      w1 = eldc[j + 1];
    } else {
      float e0 = el3[s0] + ern; e0 = (e0 >= 0.f) ? e0 : 0.2f * e0;
      float e1 = el3[s1] + ern; e1 = (e1 >= 0.f) ? e1 : 0.2f * e1;
      w0 = __expf(e0 - m) * inv;
      w1 = __expf(e1 - m) * inv;
    }
    if (act2) {
      unsigned int h0 = hp3[(size_t)s0 * 32 + t];
      unsigned int h1 = hp3[(size_t)s1 * 32 + t];
      ax += w0 * __uint_as_float(h0 << 16);
      ay += w0 * __uint_as_float(h0 & 0xffff0000u);
      bx += w1 * __uint_as_float(h1 << 16);
      by += w1 * __uint_as_float(h1 & 0xffff0000u);
    }
  }
  if (j < deg) {
    int s0 = srcs[i0 + j];
    float w0;
    if (j < MAXE) {
      w0 = eldc[j];
    } else {
      float e0 = el3[s0] + ern; e0 = (e0 >= 0.f) ? e0 : 0.2f * e0;
      w0 = __expf(e0 - m) * inv;
    }
    if (act2) {
      unsigned int h0 = hp3[(size_t)s0 * 32 + t];
      ax += w0 * __uint_as_float(h0 << 16);
      ay += w0 * __uint_as_float(h0 & 0xffff0000u);
    }
  }
  float z0 = ax + bx + (act2 ? bias[2 * t] : 0.f);
  float z1 = ay + by + (act2 ? bias[2 * t + 1] : 0.f);
  float mx = act2 ? fmaxf(z0, z1) : -1e30f;
  for (int off = 32; off > 0; off >>= 1) mx = fmaxf(mx, __shfl_xor(mx, off));
  float sm = act2 ? (__expf(z0 - mx) + __expf(z1 - mx)) : 0.f;
  for (int off = 32; off > 0; off >>= 1) sm += __shfl_xor(sm, off);
  float ls = __logf(sm);
  if (act2) {
    float2 r;
    r.x = z0 - mx - ls;
    r.y = z1 - mx - ls;
    *reinterpret_cast<float2*>(out + (size_t)n * NCLASS + 2 * t) = r;
  }
}

extern "C" void kernel_launch(void* const* d_in, const int* in_sizes, int n_in,
                              void* d_out, int out_size, void* d_ws, size_t ws_size,
                              hipStream_t stream) {
  const float* x   = (const float*)d_in[0];
  const int* edges = (const int*)d_in[1];
  const float* W1  = (const float*)d_in[2];
  const float* al1 = (const float*)d_in[3];
  const float* ar1 = (const float*)d_in[4];
  const float* b1  = (const float*)d_in[5];
  const float* W2  = (const float*)d_in[6];
  const float* al2 = (const float*)d_in[7];
  const float* ar2 = (const float*)d_in[8];
  const float* b2  = (const float*)d_in[9];
  const float* W3  = (const float*)d_in[10];
  const float* al3 = (const float*)d_in[11];
  const float* ar3 = (const float*)d_in[12];
  const float* b3  = (const float*)d_in[13];
  float* out = (float*)d_out;

  const size_t N = N_NODES, E = N_EDGES;
  float* el  = (float*)d_ws;             // [N,4]
  float* er  = el + N * 4;               // [N,4]
  float* el3 = er + N * 4;               // [N]
  float* er3 = el3 + N;                  // [N]
  __hip_bfloat16* xb = (__hip_bfloat16*)(er3 + N);  // [N,256]
  __hip_bfloat16* hb = xb + N * 256;     // [N,256]
  __hip_bfloat16* ob = hb + N * 256;     // [N,256]
  __hip_bfloat16* h3b = ob + N * 256;    // [N,64]
  __hip_bfloat16* WT = h3b + N * 64;     // [256,256]
  __hip_bfloat16* WT3 = WT + 256 * 256;  // [64,256]
  int* rowp   = (int*)(WT3 + 64 * 256);  // [N+1]
  int* cursor = rowp + (N + 1);          // [N]
  int* srcs   = cursor + N;              // [E]
  int* deg    = srcs + E;                // [N]
  int* bsums  = deg + N;                 // [256]
  int* s32    = bsums + 256;             // [E]
  int* d32    = s32 + E;                 // [E]
  int* flag   = d32 + E;                 // [1]

  hipMemsetAsync(deg, 0, N * sizeof(int), stream);
  detect_i64<<<1, 64, 0, stream>>>(edges, flag);
  int eb = (int)((E + 255) / 256);
  norm_count<<<eb, 256, 0, stream>>>(edges, flag, s32, d32, deg);
  int nb = (int)((N + 255) / 256);
  scan_bsum<<<nb, 256, 0, stream>>>(deg, bsums);
  scan_offsets<<<1, 256, 0, stream>>>(bsums, rowp, nb);
  scan_final<<<nb, 256, 0, stream>>>(deg, bsums, rowp, cursor);
  scatter_edges<<<eb, 256, 0, stream>>>(s32, d32, cursor, srcs);

  dim3 gg((unsigned)((N + 127) / 128), 2);  // 391 x 2
  dim3 g3((unsigned)((N + 127) / 128), 1);

  // layer 1
  cast_x<<<(unsigned)(N * 256 / 4 / 256), 256, 0, stream>>>(x, xb);
  tr_w<<<256, 256, 0, stream>>>(W1, WT);
  gemm_gat12<<<gg, 256, 0, stream>>>(xb, WT, al1, ar1, hb, el, er);
  agg_fused<<<(unsigned)N, 128, 0, stream>>>(hb, el, er, b1, rowp, srcs, ob);
  // layer 2
  tr_w<<<256, 256, 0, stream>>>(W2, WT);
  gemm_gat12<<<gg, 256, 0, stream>>>(ob, WT, al2, ar2, hb, el, er);
  agg_fused<<<(unsigned)N, 128, 0, stream>>>(hb, el, er, b2, rowp, srcs, ob);
  // layer 3 + fused log_softmax
  tr_w3<<<64, 256, 0, stream>>>(W3, WT3);
  gemm_gat3<<<g3, 256, 0, stream>>>(ob, WT3, al3, ar3, h3b, el3, er3);
  agg_cls_fused<<<(unsigned)N, 64, 0, stream>>>(h3b, el3, er3, b3, rowp, srcs, out);
}